// Round 6
// baseline (217.719 us; speedup 1.0000x reference)
//
#include <hip/hip_runtime.h>
#include <hip/hip_bf16.h>
#include <math.h>

#define BATCH 16
#define CCH 256
#define HW 1024
#define NH 8
#define HD 32
// 1/sqrt(32) * log2(e): Q pre-scaled so softmax uses raw v_exp_f32 (base-2)
#define QSCALE 0.25500526954123462f

typedef __attribute__((ext_vector_type(8))) short bf16x8;  // 8 bf16 = 4 VGPRs
typedef __attribute__((ext_vector_type(4))) short bf16x4;  // 4 bf16 = 2 VGPRs
typedef __attribute__((ext_vector_type(4))) float f32x4;

__device__ __forceinline__ unsigned short bf16bits(float f) {
  __hip_bfloat16 h = __float2bfloat16(f);
  return *(unsigned short*)&h;
}

// async global->LDS, 16B per lane; lds dest must be wave-uniform base (+lane*16)
__device__ __forceinline__ void gload16(const void* g, void* l) {
  __builtin_amdgcn_global_load_lds(
      (const __attribute__((address_space(1))) unsigned int*)g,
      (__attribute__((address_space(3))) unsigned int*)l, 16, 0, 0);
}

// pack hi16 of two floats (truncation-to-bf16): dst = (hi(b)<<16)|hi(a)
__device__ __forceinline__ unsigned int pack_bf16_trunc(float a, float b) {
  return __builtin_amdgcn_perm(__float_as_uint(b), __float_as_uint(a), 0x07060302u);
}

// ---------------------------------------------------------------------------
// Convert weights fp32 -> bf16 (same layout, k contiguous)
// ---------------------------------------------------------------------------
__global__ __launch_bounds__(256) void cvt_w(const float* __restrict__ w,
                                             unsigned short* __restrict__ wb, int n4) {
  int i = blockIdx.x * 256 + threadIdx.x;
  if (i >= n4) return;
  float4 v = ((const float4*)w)[i];
  ushort4 o;
  o.x = bf16bits(v.x); o.y = bf16bits(v.y); o.z = bf16bits(v.z); o.w = bf16bits(v.w);
  ((ushort4*)wb)[i] = o;
}

// ---------------------------------------------------------------------------
// Zero the fused-GN stats accumulators (d_ws is poisoned 0xAA every call)
// ---------------------------------------------------------------------------
__global__ __launch_bounds__(256) void zero_stats(float* __restrict__ gstats) {
  gstats[threadIdx.x] = 0.f;
}

// ---------------------------------------------------------------------------
// Transpose-convert x fp32 [b][c][p] -> xt bf16 [b][p][c]
// ---------------------------------------------------------------------------
__global__ __launch_bounds__(256) void cvt_x(const float* __restrict__ x,
                                             unsigned short* __restrict__ xt) {
  __shared__ unsigned short tile[64][72];
  const int t = threadIdx.x;
  const int p0 = blockIdx.x * 64;
  const int c0 = blockIdx.y * 64;
  const int b = blockIdx.z;
  const float* xb = x + (size_t)b * CCH * HW;
#pragma unroll
  for (int i = 0; i < 4; ++i) {
    int f = i * 256 + t;
    int c = f >> 4, p4 = f & 15;
    float4 v = *(const float4*)(xb + (size_t)(c0 + c) * HW + p0 + p4 * 4);
    tile[p4 * 4 + 0][c] = bf16bits(v.x);
    tile[p4 * 4 + 1][c] = bf16bits(v.y);
    tile[p4 * 4 + 2][c] = bf16bits(v.z);
    tile[p4 * 4 + 3][c] = bf16bits(v.w);
  }
  __syncthreads();
  unsigned short* xtb = xt + (size_t)b * HW * CCH;
#pragma unroll
  for (int i = 0; i < 4; ++i) {
    int f = i * 256 + t;
    int p = f >> 4, c4 = f & 15;
    ushort4 v = *(const ushort4*)&tile[p][c4 * 4];
    *(ushort4*)(xtb + (size_t)(p0 + p) * CCH + c0 + c4 * 4) = v;
  }
}

// ---------------------------------------------------------------------------
// Kernel 1: qkv MFMA GEMM (128x128 tile, BK=64, global_load_lds 16B).
// Q written with QSCALE (1/sqrt(d) * log2e); K/V fragment-major (see r5 notes).
// ---------------------------------------------------------------------------
__global__ __launch_bounds__(256) void qkv_mfma(const unsigned short* __restrict__ Wb,
                                                const unsigned short* __restrict__ Xt,
                                                unsigned short* __restrict__ Qb,
                                                unsigned short* __restrict__ Kf,
                                                unsigned short* __restrict__ Vf) {
  __shared__ unsigned short A_l[8 * 128 * 8];  // 16 KB
  __shared__ unsigned short B_l[8 * 128 * 8];  // 16 KB
  const int t = threadIdx.x;
  const int wave = t >> 6, lane = t & 63;
  const int quad = lane >> 4, n16 = lane & 15;
  const int o0 = blockIdx.x * 128;
  const int p0 = blockIdx.y * 128;
  const int b = blockIdx.z;
  const int wm = (wave >> 1) * 64, wn = (wave & 1) * 64;
  const unsigned short* Xb = Xt + (size_t)b * (HW * CCH);

  f32x4 acc[4][4] = {};
  for (int k0 = 0; k0 < CCH; k0 += 64) {
#pragma unroll
    for (int i = 0; i < 4; ++i) {
      int f = i * 256 + t;
      int kc = f >> 7, m = f & 127;
      int dst = (i * 256 + wave * 64) * 8;  // wave-uniform
      gload16(Wb + (size_t)(o0 + m) * CCH + k0 + kc * 8, &A_l[dst]);
      gload16(Xb + (size_t)(p0 + m) * CCH + k0 + kc * 8, &B_l[dst]);
    }
    __syncthreads();
#pragma unroll
    for (int ks = 0; ks < 2; ++ks) {
      bf16x8 af[4], bfr[4];
#pragma unroll
      for (int mi = 0; mi < 4; ++mi)
        af[mi] = *(const bf16x8*)&A_l[((ks * 4 + quad) * 128 + wm + mi * 16 + n16) * 8];
#pragma unroll
      for (int ni = 0; ni < 4; ++ni)
        bfr[ni] = *(const bf16x8*)&B_l[((ks * 4 + quad) * 128 + wn + ni * 16 + n16) * 8];
#pragma unroll
      for (int mi = 0; mi < 4; ++mi)
#pragma unroll
        for (int ni = 0; ni < 4; ++ni)
          acc[mi][ni] = __builtin_amdgcn_mfma_f32_16x16x32_bf16(af[mi], bfr[ni], acc[mi][ni], 0, 0, 0);
    }
    __syncthreads();
  }
  const int three = o0 >> 8;
#pragma unroll
  for (int mi = 0; mi < 4; ++mi) {
    int o = o0 + wm + mi * 16 + quad * 4;
    int head = (o >> 5) & 7;           // constant across r (d0+3 <= 31)
    int d0 = (mi & 1) * 16 + quad * 4; // o & 31
    size_t bh64 = (size_t)(b * NH + head) * 64;
    size_t bh_base = (size_t)(b * NH + head) * (HW * HD);
#pragma unroll
    for (int ni = 0; ni < 4; ++ni) {
      int p = p0 + wn + ni * 16 + n16;
      if (three == 0) {
        ushort4 st;
        st.x = bf16bits(acc[mi][ni][0] * QSCALE);
        st.y = bf16bits(acc[mi][ni][1] * QSCALE);
        st.z = bf16bits(acc[mi][ni][2] * QSCALE);
        st.w = bf16bits(acc[mi][ni][3] * QSCALE);
        *(ushort4*)&Qb[bh_base + (size_t)p * HD + d0] = st;
      } else if (three == 1) {
        int kb = p >> 4;
        size_t chunk = (bh64 + kb) * 64 + (d0 >> 3) * 16 + n16;
        ushort4 st;
        st.x = bf16bits(acc[mi][ni][0]);
        st.y = bf16bits(acc[mi][ni][1]);
        st.z = bf16bits(acc[mi][ni][2]);
        st.w = bf16bits(acc[mi][ni][3]);
        *(ushort4*)&Kf[chunk * 8 + (d0 & 7)] = st;
      } else {
        int kb = p >> 4;
        size_t base = (bh64 + kb) * 64 + (n16 >> 2) * 16 + quad * 4;
#pragma unroll
        for (int r = 0; r < 4; ++r)
          Vf[(base + r) * 8 + (mi & 1) * 4 + (n16 & 3)] = bf16bits(acc[mi][ni][r]);
      }
    }
  }
}

// ---------------------------------------------------------------------------
// Kernel 2: MFMA flash attention v4 -- 32 queries/wave (2 Q-frags share every
// K/V LDS read), exp2 softmax (scale folded into Q), v_perm truncation pack.
// Block = 4 waves x 32 q = 128 queries of one bh. 8 qtiles x 128 bh = 1024 blk.
// ---------------------------------------------------------------------------
__global__ __launch_bounds__(256) void attn_mfma(const unsigned short* __restrict__ Q,
                                                 const unsigned short* __restrict__ Kf,
                                                 const unsigned short* __restrict__ Vf,
                                                 unsigned short* __restrict__ Ab) {
  __shared__ unsigned short Ksh[4 * 64 * 8];  // 4 KB
  __shared__ unsigned short Vsh[4 * 64 * 8];  // 4 KB
  const int t = threadIdx.x;
  const int lane = t & 63;
  const int quad = lane >> 4, n16 = lane & 15;
  const int wave = t >> 6;
  // XCD swizzle: all 8 query-tiles of a (b,head) on one XCD slot
  const int id = blockIdx.y * 8 + blockIdx.x;  // 1024 blocks
  const int xcd = id & 7, jj = id >> 3;        // jj 0..127
  const int bh = xcd * 16 + (jj >> 3);
  const int qtile = jj & 7;
  const int i0w = qtile * 128 + wave * 32;
  const size_t hb = (size_t)bh * (HW * HD);
  const size_t fb = (size_t)bh * 64 * 64 * 8;

  // Q frags (B operand): B[k=quad*8+j][n=n16] = Q[query][d]
  bf16x8 qf0 = *(const bf16x8*)((const short*)Q + hb + (size_t)(i0w + n16) * HD + quad * 8);
  bf16x8 qf1 = *(const bf16x8*)((const short*)Q + hb + (size_t)(i0w + 16 + n16) * HD + quad * 8);
  // O[group][dhalf][parity]
  f32x4 O000 = {0,0,0,0}, O001 = {0,0,0,0}, O010 = {0,0,0,0}, O011 = {0,0,0,0};
  f32x4 O100 = {0,0,0,0}, O101 = {0,0,0,0}, O110 = {0,0,0,0}, O111 = {0,0,0,0};
  const f32x4 zero = {0.f, 0.f, 0.f, 0.f};
  float l0 = 0.f, l1 = 0.f;

  for (int jt = 0; jt < 16; ++jt) {
    gload16(Kf + fb + ((size_t)jt * 4 * 64 + t) * 8, &Ksh[t * 8]);
    gload16(Vf + fb + ((size_t)jt * 4 * 64 + t) * 8, &Vsh[t * 8]);
    __syncthreads();
    f32x4 S0[4], S1[4];
#pragma unroll
    for (int kk = 0; kk < 4; ++kk) {
      bf16x8 kfr = *(const bf16x8*)&Ksh[(kk * 64 + lane) * 8];
      S0[kk] = __builtin_amdgcn_mfma_f32_16x16x32_bf16(kfr, qf0, zero, 0, 0, 0);
      S1[kk] = __builtin_amdgcn_mfma_f32_16x16x32_bf16(kfr, qf1, zero, 0, 0, 0);
    }
    bf16x4 pf0[4], pf1[4];
#pragma unroll
    for (int kk = 0; kk < 4; ++kk) {
      float a0 = __builtin_amdgcn_exp2f(S0[kk][0]);
      float a1 = __builtin_amdgcn_exp2f(S0[kk][1]);
      float a2 = __builtin_amdgcn_exp2f(S0[kk][2]);
      float a3 = __builtin_amdgcn_exp2f(S0[kk][3]);
      l0 += (a0 + a1) + (a2 + a3);
      unsigned int plo = pack_bf16_trunc(a0, a1);
      unsigned int phi = pack_bf16_trunc(a2, a3);
      unsigned int* pw = (unsigned int*)&pf0[kk];
      pw[0] = plo; pw[1] = phi;
      float b0 = __builtin_amdgcn_exp2f(S1[kk][0]);
      float b1 = __builtin_amdgcn_exp2f(S1[kk][1]);
      float b2 = __builtin_amdgcn_exp2f(S1[kk][2]);
      float b3 = __builtin_amdgcn_exp2f(S1[kk][3]);
      l1 += (b0 + b1) + (b2 + b3);
      unsigned int qlo = pack_bf16_trunc(b0, b1);
      unsigned int qhi = pack_bf16_trunc(b2, b3);
      unsigned int* qw = (unsigned int*)&pf1[kk];
      qw[0] = qlo; qw[1] = qhi;
    }
#pragma unroll
    for (int kk = 0; kk < 4; ++kk) {
      bf16x8 vv = *(const bf16x8*)&Vsh[(kk * 64 + lane) * 8];
      bf16x4 v0 = __builtin_shufflevector(vv, vv, 0, 1, 2, 3);
      bf16x4 v1 = __builtin_shufflevector(vv, vv, 4, 5, 6, 7);
      if (kk & 1) {
        O001 = __builtin_amdgcn_mfma_f32_16x16x16bf16_1k(pf0[kk], v0, O001, 0, 0, 0);
        O011 = __builtin_amdgcn_mfma_f32_16x16x16bf16_1k(pf0[kk], v1, O011, 0, 0, 0);
        O101 = __builtin_amdgcn_mfma_f32_16x16x16bf16_1k(pf1[kk], v0, O101, 0, 0, 0);
        O111 = __builtin_amdgcn_mfma_f32_16x16x16bf16_1k(pf1[kk], v1, O111, 0, 0, 0);
      } else {
        O000 = __builtin_amdgcn_mfma_f32_16x16x16bf16_1k(pf0[kk], v0, O000, 0, 0, 0);
        O010 = __builtin_amdgcn_mfma_f32_16x16x16bf16_1k(pf0[kk], v1, O010, 0, 0, 0);
        O100 = __builtin_amdgcn_mfma_f32_16x16x16bf16_1k(pf1[kk], v0, O100, 0, 0, 0);
        O110 = __builtin_amdgcn_mfma_f32_16x16x16bf16_1k(pf1[kk], v1, O110, 0, 0, 0);
      }
    }
    __syncthreads();
  }
  f32x4 A0, A1, B0, B1;
#pragma unroll
  for (int r = 0; r < 4; ++r) {
    A0[r] = O000[r] + O001[r]; A1[r] = O010[r] + O011[r];
    B0[r] = O100[r] + O101[r]; B1[r] = O110[r] + O111[r];
  }
  l0 += __shfl_xor(l0, 16, 64); l0 += __shfl_xor(l0, 32, 64);
  l1 += __shfl_xor(l1, 16, 64); l1 += __shfl_xor(l1, 32, 64);
  float linv0 = 1.f / l0, linv1 = 1.f / l1;
  float lq0[4], lq1[4];
#pragma unroll
  for (int r = 0; r < 4; ++r) {
    lq0[r] = __shfl(linv0, quad * 4 + r, 64);
    lq1[r] = __shfl(linv1, quad * 4 + r, 64);
  }
  const int bb = bh >> 3, head = bh & 7;
  unsigned short* dst = Ab + (size_t)bb * (HW * CCH) + head * 32;
#pragma unroll
  for (int r = 0; r < 4; ++r) {
    int p0r = i0w + quad * 4 + r;
    dst[(size_t)p0r * CCH + n16] = bf16bits(A0[r] * lq0[r]);
    dst[(size_t)p0r * CCH + 16 + n16] = bf16bits(A1[r] * lq0[r]);
    int p1r = i0w + 16 + quad * 4 + r;
    dst[(size_t)p1r * CCH + n16] = bf16bits(B0[r] * lq1[r]);
    dst[(size_t)p1r * CCH + 16 + n16] = bf16bits(B1[r] * lq1[r]);
  }
}

// ---------------------------------------------------------------------------
// Kernel 3: proj MFMA GEMM -> P bf16 [b][c][p] + fused GN partial sums
// (per-(wave,mi) group reduce -> 2 atomicAdds into gstats[bg*2..+1])
// ---------------------------------------------------------------------------
__global__ __launch_bounds__(256) void proj_mfma(const unsigned short* __restrict__ Wb,
                                                 const unsigned short* __restrict__ At,
                                                 unsigned short* __restrict__ Pb,
                                                 float* __restrict__ gstats) {
  __shared__ unsigned short A_l[8 * 128 * 8];
  __shared__ unsigned short B_l[8 * 128 * 8];
  const int t = threadIdx.x;
  const int wave = t >> 6, lane = t & 63;
  const int quad = lane >> 4, n16 = lane & 15;
  const int o0 = blockIdx.x * 128;
  const int p0 = blockIdx.y * 128;
  const int b = blockIdx.z;
  const int wm = (wave >> 1) * 64, wn = (wave & 1) * 64;
  const unsigned short* Ax = At + (size_t)b * (HW * CCH);

  f32x4 acc[4][4] = {};
  for (int k0 = 0; k0 < CCH; k0 += 64) {
#pragma unroll
    for (int i = 0; i < 4; ++i) {
      int f = i * 256 + t;
      int kc = f >> 7, m = f & 127;
      int dst = (i * 256 + wave * 64) * 8;
      gload16(Wb + (size_t)(o0 + m) * CCH + k0 + kc * 8, &A_l[dst]);
      gload16(Ax + (size_t)(p0 + m) * CCH + k0 + kc * 8, &B_l[dst]);
    }
    __syncthreads();
#pragma unroll
    for (int ks = 0; ks < 2; ++ks) {
      bf16x8 af[4], bfr[4];
#pragma unroll
      for (int mi = 0; mi < 4; ++mi)
        af[mi] = *(const bf16x8*)&A_l[((ks * 4 + quad) * 128 + wm + mi * 16 + n16) * 8];
#pragma unroll
      for (int ni = 0; ni < 4; ++ni)
        bfr[ni] = *(const bf16x8*)&B_l[((ks * 4 + quad) * 128 + wn + ni * 16 + n16) * 8];
#pragma unroll
      for (int mi = 0; mi < 4; ++mi)
#pragma unroll
        for (int ni = 0; ni < 4; ++ni)
          acc[mi][ni] = __builtin_amdgcn_mfma_f32_16x16x32_bf16(af[mi], bfr[ni], acc[mi][ni], 0, 0, 0);
    }
    __syncthreads();
  }
#pragma unroll
  for (int mi = 0; mi < 4; ++mi) {
    int obase = o0 + wm + mi * 16;       // 16-aligned; group = obase>>5 wave-uniform
    int o = obase + quad * 4;
    float s1 = 0.f, s2 = 0.f;
#pragma unroll
    for (int ni = 0; ni < 4; ++ni) {
      int p = p0 + wn + ni * 16 + n16;
#pragma unroll
      for (int r = 0; r < 4; ++r) {
        float v = acc[mi][ni][r];
        s1 += v; s2 += v * v;
        Pb[(size_t)b * (CCH * HW) + (size_t)(o + r) * HW + p] = bf16bits(v);
      }
    }
#pragma unroll
    for (int m = 1; m < 64; m <<= 1) {
      s1 += __shfl_xor(s1, m, 64);
      s2 += __shfl_xor(s2, m, 64);
    }
    if (lane == 0) {
      int bg = b * 8 + (obase >> 5);
      atomicAdd(&gstats[bg * 2], s1);
      atomicAdd(&gstats[bg * 2 + 1], s2);
    }
  }
}

// ---------------------------------------------------------------------------
// Kernel 4: out = (P - mean)*inv*gamma + beta + x   (P bf16, stats from sums)
// ---------------------------------------------------------------------------
__global__ __launch_bounds__(256) void gn_apply(const unsigned short* __restrict__ Pb,
                                                const float* __restrict__ x,
                                                const float* __restrict__ gamma,
                                                const float* __restrict__ beta,
                                                const float* __restrict__ gstats,
                                                float* __restrict__ out) {
  int i4 = blockIdx.x * 256 + threadIdx.x;
  int c = (i4 >> 8) & 255;
  int bg = i4 >> 13;
  float mean = gstats[bg * 2] * (1.f / 32768.f);
  float var = gstats[bg * 2 + 1] * (1.f / 32768.f) - mean * mean;
  float inv = rsqrtf(var + 1e-5f);
  float ga = gamma[c] * inv;
  float be = beta[c] - mean * ga;
  ushort4 pu = ((const ushort4*)Pb)[i4];
  float4 xr = ((const float4*)x)[i4];
  float4 o;
  o.x = __uint_as_float((unsigned)pu.x << 16) * ga + be + xr.x;
  o.y = __uint_as_float((unsigned)pu.y << 16) * ga + be + xr.y;
  o.z = __uint_as_float((unsigned)pu.z << 16) * ga + be + xr.z;
  o.w = __uint_as_float((unsigned)pu.w << 16) * ga + be + xr.w;
  ((float4*)out)[i4] = o;
}

// ---------------------------------------------------------------------------
extern "C" void kernel_launch(void* const* d_in, const int* in_sizes, int n_in,
                              void* d_out, int out_size, void* d_ws, size_t ws_size,
                              hipStream_t stream) {
  const float* x      = (const float*)d_in[0];
  const float* w_qkv  = (const float*)d_in[1];
  const float* w_proj = (const float*)d_in[2];
  const float* gamma  = (const float*)d_in[3];
  const float* beta   = (const float*)d_in[4];
  float* out = (float*)d_out;

  const size_t SZ = (size_t)BATCH * CCH * HW;
  unsigned short* Pb = (unsigned short*)d_ws;  // bf16 [b][c][p]
  unsigned short* Qb  = Pb + SZ;
  unsigned short* Kfr = Qb + SZ;   // frag-major K
  unsigned short* Vfr = Kfr + SZ;  // frag-major V
  unsigned short* Ab  = Vfr + SZ;
  unsigned short* Xtb = Ab + SZ;
  unsigned short* Wqb = Xtb + SZ;
  unsigned short* Wpb = Wqb + (3 * CCH * CCH);
  float* gstats = (float*)(Wpb + CCH * CCH);   // 256 floats (128 bg x {s1,s2})

  cvt_w<<<192, 256, 0, stream>>>(w_qkv, Wqb, 3 * CCH * CCH / 4);
  cvt_w<<<64, 256, 0, stream>>>(w_proj, Wpb, CCH * CCH / 4);
  zero_stats<<<1, 256, 0, stream>>>(gstats);
  cvt_x<<<dim3(16, 4, BATCH), 256, 0, stream>>>(x, Xtb);
  qkv_mfma<<<dim3(6, 8, BATCH), 256, 0, stream>>>(Wqb, Xtb, Qb, Kfr, Vfr);
  attn_mfma<<<dim3(8, 128), 256, 0, stream>>>(Qb, Kfr, Vfr, Ab);
  proj_mfma<<<dim3(2, 8, BATCH), 256, 0, stream>>>(Wpb, Ab, Pb, gstats);
  gn_apply<<<4096, 256, 0, stream>>>(Pb, x, gamma, beta, gstats, out);
}

// Round 7
// 212.644 us; speedup vs baseline: 1.0239x; 1.0239x over previous
//
#include <hip/hip_runtime.h>
#include <hip/hip_bf16.h>
#include <math.h>

#define BATCH 16
#define CCH 256
#define HW 1024
#define NH 8
#define HD 32
// 1/sqrt(32) * log2(e): Q pre-scaled so softmax uses raw v_exp_f32 (base-2)
#define QSCALE 0.25500526954123462f

typedef __attribute__((ext_vector_type(8))) short bf16x8;  // 8 bf16 = 4 VGPRs
typedef __attribute__((ext_vector_type(4))) short bf16x4;  // 4 bf16 = 2 VGPRs
typedef __attribute__((ext_vector_type(4))) float f32x4;

__device__ __forceinline__ unsigned short bf16bits(float f) {
  __hip_bfloat16 h = __float2bfloat16(f);
  return *(unsigned short*)&h;
}

// async global->LDS, 16B per lane; lds dest must be wave-uniform base (+lane*16)
__device__ __forceinline__ void gload16(const void* g, void* l) {
  __builtin_amdgcn_global_load_lds(
      (const __attribute__((address_space(1))) unsigned int*)g,
      (__attribute__((address_space(3))) unsigned int*)l, 16, 0, 0);
}

// pack hi16 of two floats (truncation-to-bf16): dst = (hi(b)<<16)|hi(a)
__device__ __forceinline__ unsigned int pack_bf16_trunc(float a, float b) {
  return __builtin_amdgcn_perm(__float_as_uint(b), __float_as_uint(a), 0x07060302u);
}

// ---------------------------------------------------------------------------
// prep: convert both weight tensors fp32->bf16 and zero the GN accumulators.
// Blocks 0..191 -> w_qkv, 192..255 -> w_proj; block 255 also zeros gstats.
// ---------------------------------------------------------------------------
__global__ __launch_bounds__(256) void prep(const float* __restrict__ wqkv,
                                            const float* __restrict__ wproj,
                                            unsigned short* __restrict__ wqb,
                                            unsigned short* __restrict__ wpb,
                                            float* __restrict__ gstats) {
  int blk = blockIdx.x;
  const float* src;
  unsigned short* dst;
  int i;
  if (blk < 192) {
    src = wqkv; dst = wqb; i = blk * 256 + threadIdx.x;
  } else {
    src = wproj; dst = wpb; i = (blk - 192) * 256 + threadIdx.x;
  }
  float4 v = ((const float4*)src)[i];
  ushort4 o;
  o.x = bf16bits(v.x); o.y = bf16bits(v.y); o.z = bf16bits(v.z); o.w = bf16bits(v.w);
  ((ushort4*)dst)[i] = o;
  if (blk == 255) gstats[threadIdx.x] = 0.f;
}

// ---------------------------------------------------------------------------
// Transpose-convert x fp32 [b][c][p] -> xt bf16 [b][p][c]
// ---------------------------------------------------------------------------
__global__ __launch_bounds__(256) void cvt_x(const float* __restrict__ x,
                                             unsigned short* __restrict__ xt) {
  __shared__ unsigned short tile[64][72];
  const int t = threadIdx.x;
  const int p0 = blockIdx.x * 64;
  const int c0 = blockIdx.y * 64;
  const int b = blockIdx.z;
  const float* xb = x + (size_t)b * CCH * HW;
#pragma unroll
  for (int i = 0; i < 4; ++i) {
    int f = i * 256 + t;
    int c = f >> 4, p4 = f & 15;
    float4 v = *(const float4*)(xb + (size_t)(c0 + c) * HW + p0 + p4 * 4);
    tile[p4 * 4 + 0][c] = bf16bits(v.x);
    tile[p4 * 4 + 1][c] = bf16bits(v.y);
    tile[p4 * 4 + 2][c] = bf16bits(v.z);
    tile[p4 * 4 + 3][c] = bf16bits(v.w);
  }
  __syncthreads();
  unsigned short* xtb = xt + (size_t)b * HW * CCH;
#pragma unroll
  for (int i = 0; i < 4; ++i) {
    int f = i * 256 + t;
    int p = f >> 4, c4 = f & 15;
    ushort4 v = *(const ushort4*)&tile[p][c4 * 4];
    *(ushort4*)(xtb + (size_t)(p0 + p) * CCH + c0 + c4 * 4) = v;
  }
}

// ---------------------------------------------------------------------------
// Kernel 1: qkv MFMA GEMM (128x128 tile, BK=64, global_load_lds 16B).
// Q written with QSCALE (1/sqrt(d) * log2e); K/V fragment-major.
// ---------------------------------------------------------------------------
__global__ __launch_bounds__(256) void qkv_mfma(const unsigned short* __restrict__ Wb,
                                                const unsigned short* __restrict__ Xt,
                                                unsigned short* __restrict__ Qb,
                                                unsigned short* __restrict__ Kf,
                                                unsigned short* __restrict__ Vf) {
  __shared__ unsigned short A_l[8 * 128 * 8];  // 16 KB
  __shared__ unsigned short B_l[8 * 128 * 8];  // 16 KB
  const int t = threadIdx.x;
  const int wave = t >> 6, lane = t & 63;
  const int quad = lane >> 4, n16 = lane & 15;
  const int o0 = blockIdx.x * 128;
  const int p0 = blockIdx.y * 128;
  const int b = blockIdx.z;
  const int wm = (wave >> 1) * 64, wn = (wave & 1) * 64;
  const unsigned short* Xb = Xt + (size_t)b * (HW * CCH);

  f32x4 acc[4][4] = {};
  for (int k0 = 0; k0 < CCH; k0 += 64) {
#pragma unroll
    for (int i = 0; i < 4; ++i) {
      int f = i * 256 + t;
      int kc = f >> 7, m = f & 127;
      int dst = (i * 256 + wave * 64) * 8;  // wave-uniform
      gload16(Wb + (size_t)(o0 + m) * CCH + k0 + kc * 8, &A_l[dst]);
      gload16(Xb + (size_t)(p0 + m) * CCH + k0 + kc * 8, &B_l[dst]);
    }
    __syncthreads();
#pragma unroll
    for (int ks = 0; ks < 2; ++ks) {
      bf16x8 af[4], bfr[4];
#pragma unroll
      for (int mi = 0; mi < 4; ++mi)
        af[mi] = *(const bf16x8*)&A_l[((ks * 4 + quad) * 128 + wm + mi * 16 + n16) * 8];
#pragma unroll
      for (int ni = 0; ni < 4; ++ni)
        bfr[ni] = *(const bf16x8*)&B_l[((ks * 4 + quad) * 128 + wn + ni * 16 + n16) * 8];
#pragma unroll
      for (int mi = 0; mi < 4; ++mi)
#pragma unroll
        for (int ni = 0; ni < 4; ++ni)
          acc[mi][ni] = __builtin_amdgcn_mfma_f32_16x16x32_bf16(af[mi], bfr[ni], acc[mi][ni], 0, 0, 0);
    }
    __syncthreads();
  }
  const int three = o0 >> 8;
#pragma unroll
  for (int mi = 0; mi < 4; ++mi) {
    int o = o0 + wm + mi * 16 + quad * 4;
    int head = (o >> 5) & 7;           // constant across r (d0+3 <= 31)
    int d0 = (mi & 1) * 16 + quad * 4; // o & 31
    size_t bh64 = (size_t)(b * NH + head) * 64;
    size_t bh_base = (size_t)(b * NH + head) * (HW * HD);
#pragma unroll
    for (int ni = 0; ni < 4; ++ni) {
      int p = p0 + wn + ni * 16 + n16;
      if (three == 0) {
        ushort4 st;
        st.x = bf16bits(acc[mi][ni][0] * QSCALE);
        st.y = bf16bits(acc[mi][ni][1] * QSCALE);
        st.z = bf16bits(acc[mi][ni][2] * QSCALE);
        st.w = bf16bits(acc[mi][ni][3] * QSCALE);
        *(ushort4*)&Qb[bh_base + (size_t)p * HD + d0] = st;
      } else if (three == 1) {
        int kb = p >> 4;
        size_t chunk = (bh64 + kb) * 64 + (d0 >> 3) * 16 + n16;
        ushort4 st;
        st.x = bf16bits(acc[mi][ni][0]);
        st.y = bf16bits(acc[mi][ni][1]);
        st.z = bf16bits(acc[mi][ni][2]);
        st.w = bf16bits(acc[mi][ni][3]);
        *(ushort4*)&Kf[chunk * 8 + (d0 & 7)] = st;
      } else {
        int kb = p >> 4;
        size_t base = (bh64 + kb) * 64 + (n16 >> 2) * 16 + quad * 4;
#pragma unroll
        for (int r = 0; r < 4; ++r)
          Vf[(base + r) * 8 + (mi & 1) * 4 + (n16 & 3)] = bf16bits(acc[mi][ni][r]);
      }
    }
  }
}

// ---------------------------------------------------------------------------
// Kernel 2: MFMA flash attention v5 -- r5's 16 queries/wave structure (48 VGPR,
// no spills) + exp2 softmax (scale folded into Q) + v_perm truncation pack.
// Block = 4 waves x 16 q = 64 queries of one bh; waves share K/V LDS tile.
// ---------------------------------------------------------------------------
__global__ __launch_bounds__(256) void attn_mfma(const unsigned short* __restrict__ Q,
                                                 const unsigned short* __restrict__ Kf,
                                                 const unsigned short* __restrict__ Vf,
                                                 unsigned short* __restrict__ Ab) {
  __shared__ unsigned short Ksh[4 * 64 * 8];  // 4 KB
  __shared__ unsigned short Vsh[4 * 64 * 8];  // 4 KB
  const int t = threadIdx.x;
  const int lane = t & 63;
  const int quad = lane >> 4, n16 = lane & 15;
  const int wave = t >> 6;
  // XCD swizzle: all 16 query-tiles of a (b,head) on one XCD slot
  const int id = blockIdx.y * 16 + blockIdx.x;   // 2048 blocks
  const int xcd = id & 7, jj = id >> 3;
  const int bh = xcd * 16 + (jj >> 4);
  const int qtile = jj & 15;
  const int i0w = qtile * 64 + wave * 16;
  const size_t hb = (size_t)bh * (HW * HD);
  const size_t fb = (size_t)bh * 64 * 64 * 8;

  // Q frag (B operand): B[k=quad*8+j][n=n16] = Q[query=n16][d=quad*8+j]
  bf16x8 qf = *(const bf16x8*)((const short*)Q + hb + (size_t)(i0w + n16) * HD + quad * 8);
  f32x4 O00 = {0.f, 0.f, 0.f, 0.f}, O01 = {0.f, 0.f, 0.f, 0.f};
  f32x4 O10 = {0.f, 0.f, 0.f, 0.f}, O11 = {0.f, 0.f, 0.f, 0.f};
  const f32x4 zero = {0.f, 0.f, 0.f, 0.f};
  float l_lane = 0.f;

  for (int jt = 0; jt < 16; ++jt) {
    gload16(Kf + fb + ((size_t)jt * 4 * 64 + t) * 8, &Ksh[t * 8]);
    gload16(Vf + fb + ((size_t)jt * 4 * 64 + t) * 8, &Vsh[t * 8]);
    __syncthreads();
    f32x4 S[4];
#pragma unroll
    for (int kk = 0; kk < 4; ++kk) {
      bf16x8 kfr = *(const bf16x8*)&Ksh[(kk * 64 + lane) * 8];
      S[kk] = __builtin_amdgcn_mfma_f32_16x16x32_bf16(kfr, qf, zero, 0, 0, 0);
    }
    bf16x4 pfA[4];
#pragma unroll
    for (int kk = 0; kk < 4; ++kk) {
      float e0 = __builtin_amdgcn_exp2f(S[kk][0]);
      float e1 = __builtin_amdgcn_exp2f(S[kk][1]);
      float e2 = __builtin_amdgcn_exp2f(S[kk][2]);
      float e3 = __builtin_amdgcn_exp2f(S[kk][3]);
      l_lane += (e0 + e1) + (e2 + e3);
      unsigned int* pw = (unsigned int*)&pfA[kk];
      pw[0] = pack_bf16_trunc(e0, e1);
      pw[1] = pack_bf16_trunc(e2, e3);
    }
#pragma unroll
    for (int kk = 0; kk < 4; ++kk) {
      bf16x8 vv = *(const bf16x8*)&Vsh[(kk * 64 + lane) * 8];
      bf16x4 v0 = __builtin_shufflevector(vv, vv, 0, 1, 2, 3);
      bf16x4 v1 = __builtin_shufflevector(vv, vv, 4, 5, 6, 7);
      if (kk & 1) {
        O01 = __builtin_amdgcn_mfma_f32_16x16x16bf16_1k(pfA[kk], v0, O01, 0, 0, 0);
        O11 = __builtin_amdgcn_mfma_f32_16x16x16bf16_1k(pfA[kk], v1, O11, 0, 0, 0);
      } else {
        O00 = __builtin_amdgcn_mfma_f32_16x16x16bf16_1k(pfA[kk], v0, O00, 0, 0, 0);
        O10 = __builtin_amdgcn_mfma_f32_16x16x16bf16_1k(pfA[kk], v1, O10, 0, 0, 0);
      }
    }
    __syncthreads();  // protect LDS before next tile's DMA
  }
  f32x4 O0, O1;
#pragma unroll
  for (int r = 0; r < 4; ++r) { O0[r] = O00[r] + O01[r]; O1[r] = O10[r] + O11[r]; }
  l_lane += __shfl_xor(l_lane, 16, 64);
  l_lane += __shfl_xor(l_lane, 32, 64);
  float linv = 1.f / l_lane;                      // valid for query = n16
  float lq[4];
#pragma unroll
  for (int r = 0; r < 4; ++r) lq[r] = __shfl(linv, quad * 4 + r, 64);
  const int bb = bh >> 3, head = bh & 7;
  unsigned short* dst = Ab + (size_t)bb * (HW * CCH) + head * 32;
#pragma unroll
  for (int r = 0; r < 4; ++r) {
    int p = i0w + quad * 4 + r;
    dst[(size_t)p * CCH + n16] = bf16bits(O0[r] * lq[r]);
    dst[(size_t)p * CCH + 16 + n16] = bf16bits(O1[r] * lq[r]);
  }
}

// ---------------------------------------------------------------------------
// Kernel 3: proj MFMA GEMM -> P bf16 [b][c][p] + fused GN partial sums
// ---------------------------------------------------------------------------
__global__ __launch_bounds__(256) void proj_mfma(const unsigned short* __restrict__ Wb,
                                                 const unsigned short* __restrict__ At,
                                                 unsigned short* __restrict__ Pb,
                                                 float* __restrict__ gstats) {
  __shared__ unsigned short A_l[8 * 128 * 8];
  __shared__ unsigned short B_l[8 * 128 * 8];
  const int t = threadIdx.x;
  const int wave = t >> 6, lane = t & 63;
  const int quad = lane >> 4, n16 = lane & 15;
  const int o0 = blockIdx.x * 128;
  const int p0 = blockIdx.y * 128;
  const int b = blockIdx.z;
  const int wm = (wave >> 1) * 64, wn = (wave & 1) * 64;
  const unsigned short* Ax = At + (size_t)b * (HW * CCH);

  f32x4 acc[4][4] = {};
  for (int k0 = 0; k0 < CCH; k0 += 64) {
#pragma unroll
    for (int i = 0; i < 4; ++i) {
      int f = i * 256 + t;
      int kc = f >> 7, m = f & 127;
      int dst = (i * 256 + wave * 64) * 8;
      gload16(Wb + (size_t)(o0 + m) * CCH + k0 + kc * 8, &A_l[dst]);
      gload16(Ax + (size_t)(p0 + m) * CCH + k0 + kc * 8, &B_l[dst]);
    }
    __syncthreads();
#pragma unroll
    for (int ks = 0; ks < 2; ++ks) {
      bf16x8 af[4], bfr[4];
#pragma unroll
      for (int mi = 0; mi < 4; ++mi)
        af[mi] = *(const bf16x8*)&A_l[((ks * 4 + quad) * 128 + wm + mi * 16 + n16) * 8];
#pragma unroll
      for (int ni = 0; ni < 4; ++ni)
        bfr[ni] = *(const bf16x8*)&B_l[((ks * 4 + quad) * 128 + wn + ni * 16 + n16) * 8];
#pragma unroll
      for (int mi = 0; mi < 4; ++mi)
#pragma unroll
        for (int ni = 0; ni < 4; ++ni)
          acc[mi][ni] = __builtin_amdgcn_mfma_f32_16x16x32_bf16(af[mi], bfr[ni], acc[mi][ni], 0, 0, 0);
    }
    __syncthreads();
  }
#pragma unroll
  for (int mi = 0; mi < 4; ++mi) {
    int obase = o0 + wm + mi * 16;       // 16-aligned; group = obase>>5 wave-uniform
    int o = obase + quad * 4;
    float s1 = 0.f, s2 = 0.f;
#pragma unroll
    for (int ni = 0; ni < 4; ++ni) {
      int p = p0 + wn + ni * 16 + n16;
#pragma unroll
      for (int r = 0; r < 4; ++r) {
        float v = acc[mi][ni][r];
        s1 += v; s2 += v * v;
        Pb[(size_t)b * (CCH * HW) + (size_t)(o + r) * HW + p] = bf16bits(v);
      }
    }
#pragma unroll
    for (int m = 1; m < 64; m <<= 1) {
      s1 += __shfl_xor(s1, m, 64);
      s2 += __shfl_xor(s2, m, 64);
    }
    if (lane == 0) {
      int bg = b * 8 + (obase >> 5);
      atomicAdd(&gstats[bg * 2], s1);
      atomicAdd(&gstats[bg * 2 + 1], s2);
    }
  }
}

// ---------------------------------------------------------------------------
// Kernel 4: out = (P - mean)*inv*gamma + beta + x   (P bf16, stats from sums)
// ---------------------------------------------------------------------------
__global__ __launch_bounds__(256) void gn_apply(const unsigned short* __restrict__ Pb,
                                                const float* __restrict__ x,
                                                const float* __restrict__ gamma,
                                                const float* __restrict__ beta,
                                                const float* __restrict__ gstats,
                                                float* __restrict__ out) {
  int i4 = blockIdx.x * 256 + threadIdx.x;
  int c = (i4 >> 8) & 255;
  int bg = i4 >> 13;
  float mean = gstats[bg * 2] * (1.f / 32768.f);
  float var = gstats[bg * 2 + 1] * (1.f / 32768.f) - mean * mean;
  float inv = rsqrtf(var + 1e-5f);
  float ga = gamma[c] * inv;
  float be = beta[c] - mean * ga;
  ushort4 pu = ((const ushort4*)Pb)[i4];
  float4 xr = ((const float4*)x)[i4];
  float4 o;
  o.x = __uint_as_float((unsigned)pu.x << 16) * ga + be + xr.x;
  o.y = __uint_as_float((unsigned)pu.y << 16) * ga + be + xr.y;
  o.z = __uint_as_float((unsigned)pu.z << 16) * ga + be + xr.z;
  o.w = __uint_as_float((unsigned)pu.w << 16) * ga + be + xr.w;
  ((float4*)out)[i4] = o;
}

// ---------------------------------------------------------------------------
extern "C" void kernel_launch(void* const* d_in, const int* in_sizes, int n_in,
                              void* d_out, int out_size, void* d_ws, size_t ws_size,
                              hipStream_t stream) {
  const float* x      = (const float*)d_in[0];
  const float* w_qkv  = (const float*)d_in[1];
  const float* w_proj = (const float*)d_in[2];
  const float* gamma  = (const float*)d_in[3];
  const float* beta   = (const float*)d_in[4];
  float* out = (float*)d_out;

  const size_t SZ = (size_t)BATCH * CCH * HW;
  unsigned short* Pb = (unsigned short*)d_ws;  // bf16 [b][c][p]
  unsigned short* Qb  = Pb + SZ;
  unsigned short* Kfr = Qb + SZ;   // frag-major K
  unsigned short* Vfr = Kfr + SZ;  // frag-major V
  unsigned short* Ab  = Vfr + SZ;
  unsigned short* Xtb = Ab + SZ;
  unsigned short* Wqb = Xtb + SZ;
  unsigned short* Wpb = Wqb + (3 * CCH * CCH);
  float* gstats = (float*)(Wpb + CCH * CCH);   // 256 floats (128 bg x {s1,s2})

  prep<<<256, 256, 0, stream>>>(w_qkv, w_proj, Wqb, Wpb, gstats);
  cvt_x<<<dim3(16, 4, BATCH), 256, 0, stream>>>(x, Xtb);
  qkv_mfma<<<dim3(6, 8, BATCH), 256, 0, stream>>>(Wqb, Xtb, Qb, Kfr, Vfr);
  attn_mfma<<<dim3(16, 128), 256, 0, stream>>>(Qb, Kfr, Vfr, Ab);
  proj_mfma<<<dim3(2, 8, BATCH), 256, 0, stream>>>(Wpb, Ab, Pb, gstats);
  gn_apply<<<4096, 256, 0, stream>>>(Pb, x, gamma, beta, gstats, out);
}

// Round 8
// 157.286 us; speedup vs baseline: 1.3842x; 1.3520x over previous
//
#include <hip/hip_runtime.h>
#include <hip/hip_bf16.h>
#include <math.h>

#define BATCH 16
#define CCH 256
#define HW 1024
#define NH 8
#define HD 32
// 1/sqrt(32) * log2(e): Q pre-scaled so softmax uses raw v_exp_f32 (base-2)
#define QSCALE 0.25500526954123462f

typedef __attribute__((ext_vector_type(8))) short bf16x8;  // 8 bf16 = 4 VGPRs
typedef __attribute__((ext_vector_type(4))) short bf16x4;  // 4 bf16 = 2 VGPRs
typedef __attribute__((ext_vector_type(4))) float f32x4;
typedef __attribute__((ext_vector_type(2))) unsigned int u32x2;

__device__ __forceinline__ unsigned short bf16bits(float f) {
  __hip_bfloat16 h = __float2bfloat16(f);
  return *(unsigned short*)&h;
}

// async global->LDS, 16B per lane; lds dest must be wave-uniform base (+lane*16)
__device__ __forceinline__ void gload16(const void* g, void* l) {
  __builtin_amdgcn_global_load_lds(
      (const __attribute__((address_space(1))) unsigned int*)g,
      (__attribute__((address_space(3))) unsigned int*)l, 16, 0, 0);
}

// pack hi16 of two floats (truncation-to-bf16): dst = (hi(b)<<16)|hi(a)
__device__ __forceinline__ unsigned int pack_bf16_trunc(float a, float b) {
  return __builtin_amdgcn_perm(__float_as_uint(b), __float_as_uint(a), 0x07060302u);
}

// ---------------------------------------------------------------------------
// prep: convert both weight tensors fp32->bf16 and zero the GN accumulators.
// ---------------------------------------------------------------------------
__global__ __launch_bounds__(256) void prep(const float* __restrict__ wqkv,
                                            const float* __restrict__ wproj,
                                            unsigned short* __restrict__ wqb,
                                            unsigned short* __restrict__ wpb,
                                            float* __restrict__ gstats) {
  int blk = blockIdx.x;
  const float* src;
  unsigned short* dst;
  int i;
  if (blk < 192) {
    src = wqkv; dst = wqb; i = blk * 256 + threadIdx.x;
  } else {
    src = wproj; dst = wpb; i = (blk - 192) * 256 + threadIdx.x;
  }
  float4 v = ((const float4*)src)[i];
  ushort4 o;
  o.x = bf16bits(v.x); o.y = bf16bits(v.y); o.z = bf16bits(v.z); o.w = bf16bits(v.w);
  ((ushort4*)dst)[i] = o;
  if (blk == 255) gstats[threadIdx.x] = 0.f;
}

// ---------------------------------------------------------------------------
// Transpose-convert x fp32 [b][c][p] -> xt bf16 [b][p][c]
// ---------------------------------------------------------------------------
__global__ __launch_bounds__(256) void cvt_x(const float* __restrict__ x,
                                             unsigned short* __restrict__ xt) {
  __shared__ unsigned short tile[64][72];
  const int t = threadIdx.x;
  const int p0 = blockIdx.x * 64;
  const int c0 = blockIdx.y * 64;
  const int b = blockIdx.z;
  const float* xb = x + (size_t)b * CCH * HW;
#pragma unroll
  for (int i = 0; i < 4; ++i) {
    int f = i * 256 + t;
    int c = f >> 4, p4 = f & 15;
    float4 v = *(const float4*)(xb + (size_t)(c0 + c) * HW + p0 + p4 * 4);
    tile[p4 * 4 + 0][c] = bf16bits(v.x);
    tile[p4 * 4 + 1][c] = bf16bits(v.y);
    tile[p4 * 4 + 2][c] = bf16bits(v.z);
    tile[p4 * 4 + 3][c] = bf16bits(v.w);
  }
  __syncthreads();
  unsigned short* xtb = xt + (size_t)b * HW * CCH;
#pragma unroll
  for (int i = 0; i < 4; ++i) {
    int f = i * 256 + t;
    int p = f >> 4, c4 = f & 15;
    ushort4 v = *(const ushort4*)&tile[p][c4 * 4];
    *(ushort4*)(xtb + (size_t)(p0 + p) * CCH + c0 + c4 * 4) = v;
  }
}

// ---------------------------------------------------------------------------
// Kernel 1: qkv MFMA GEMM (128x128 tile, BK=64, global_load_lds 16B).
// Q written with QSCALE (1/sqrt(d) * log2e); K/V fragment-major.
// ---------------------------------------------------------------------------
__global__ __launch_bounds__(256) void qkv_mfma(const unsigned short* __restrict__ Wb,
                                                const unsigned short* __restrict__ Xt,
                                                unsigned short* __restrict__ Qb,
                                                unsigned short* __restrict__ Kf,
                                                unsigned short* __restrict__ Vf) {
  __shared__ unsigned short A_l[8 * 128 * 8];  // 16 KB
  __shared__ unsigned short B_l[8 * 128 * 8];  // 16 KB
  const int t = threadIdx.x;
  const int wave = t >> 6, lane = t & 63;
  const int quad = lane >> 4, n16 = lane & 15;
  const int o0 = blockIdx.x * 128;
  const int p0 = blockIdx.y * 128;
  const int b = blockIdx.z;
  const int wm = (wave >> 1) * 64, wn = (wave & 1) * 64;
  const unsigned short* Xb = Xt + (size_t)b * (HW * CCH);

  f32x4 acc[4][4] = {};
  for (int k0 = 0; k0 < CCH; k0 += 64) {
#pragma unroll
    for (int i = 0; i < 4; ++i) {
      int f = i * 256 + t;
      int kc = f >> 7, m = f & 127;
      int dst = (i * 256 + wave * 64) * 8;  // wave-uniform
      gload16(Wb + (size_t)(o0 + m) * CCH + k0 + kc * 8, &A_l[dst]);
      gload16(Xb + (size_t)(p0 + m) * CCH + k0 + kc * 8, &B_l[dst]);
    }
    __syncthreads();
#pragma unroll
    for (int ks = 0; ks < 2; ++ks) {
      bf16x8 af[4], bfr[4];
#pragma unroll
      for (int mi = 0; mi < 4; ++mi)
        af[mi] = *(const bf16x8*)&A_l[((ks * 4 + quad) * 128 + wm + mi * 16 + n16) * 8];
#pragma unroll
      for (int ni = 0; ni < 4; ++ni)
        bfr[ni] = *(const bf16x8*)&B_l[((ks * 4 + quad) * 128 + wn + ni * 16 + n16) * 8];
#pragma unroll
      for (int mi = 0; mi < 4; ++mi)
#pragma unroll
        for (int ni = 0; ni < 4; ++ni)
          acc[mi][ni] = __builtin_amdgcn_mfma_f32_16x16x32_bf16(af[mi], bfr[ni], acc[mi][ni], 0, 0, 0);
    }
    __syncthreads();
  }
  const int three = o0 >> 8;
#pragma unroll
  for (int mi = 0; mi < 4; ++mi) {
    int o = o0 + wm + mi * 16 + quad * 4;
    int head = (o >> 5) & 7;           // constant across r (d0+3 <= 31)
    int d0 = (mi & 1) * 16 + quad * 4; // o & 31
    size_t bh64 = (size_t)(b * NH + head) * 64;
    size_t bh_base = (size_t)(b * NH + head) * (HW * HD);
#pragma unroll
    for (int ni = 0; ni < 4; ++ni) {
      int p = p0 + wn + ni * 16 + n16;
      if (three == 0) {
        ushort4 st;
        st.x = bf16bits(acc[mi][ni][0] * QSCALE);
        st.y = bf16bits(acc[mi][ni][1] * QSCALE);
        st.z = bf16bits(acc[mi][ni][2] * QSCALE);
        st.w = bf16bits(acc[mi][ni][3] * QSCALE);
        *(ushort4*)&Qb[bh_base + (size_t)p * HD + d0] = st;
      } else if (three == 1) {
        int kb = p >> 4;
        size_t chunk = (bh64 + kb) * 64 + (d0 >> 3) * 16 + n16;
        ushort4 st;
        st.x = bf16bits(acc[mi][ni][0]);
        st.y = bf16bits(acc[mi][ni][1]);
        st.z = bf16bits(acc[mi][ni][2]);
        st.w = bf16bits(acc[mi][ni][3]);
        *(ushort4*)&Kf[chunk * 8 + (d0 & 7)] = st;
      } else {
        int kb = p >> 4;
        size_t base = (bh64 + kb) * 64 + (n16 >> 2) * 16 + quad * 4;
#pragma unroll
        for (int r = 0; r < 4; ++r)
          Vf[(base + r) * 8 + (mi & 1) * 4 + (n16 & 3)] = bf16bits(acc[mi][ni][r]);
      }
    }
  }
}

// ---------------------------------------------------------------------------
// Kernel 2: MFMA flash attention v6 -- r5 structure, exp2 softmax, clean
// bit_cast pack (no address-taken locals), VGPR capped via launch_bounds.
// Block = 4 waves x 16 q = 64 queries of one bh; waves share K/V LDS tile.
// ---------------------------------------------------------------------------
__global__ __launch_bounds__(256, 8) void attn_mfma(const unsigned short* __restrict__ Q,
                                                    const unsigned short* __restrict__ Kf,
                                                    const unsigned short* __restrict__ Vf,
                                                    unsigned short* __restrict__ Ab) {
  __shared__ unsigned short Ksh[4 * 64 * 8];  // 4 KB
  __shared__ unsigned short Vsh[4 * 64 * 8];  // 4 KB
  const int t = threadIdx.x;
  const int lane = t & 63;
  const int quad = lane >> 4, n16 = lane & 15;
  const int wave = t >> 6;
  // XCD swizzle: all 16 query-tiles of a (b,head) on one XCD slot
  const int id = blockIdx.y * 16 + blockIdx.x;   // 2048 blocks
  const int xcd = id & 7, jj = id >> 3;
  const int bh = xcd * 16 + (jj >> 4);
  const int qtile = jj & 15;
  const int i0w = qtile * 64 + wave * 16;
  const size_t hb = (size_t)bh * (HW * HD);
  const size_t fb = (size_t)bh * 64 * 64 * 8;

  // Q frag (B operand): B[k=quad*8+j][n=n16] = Q[query=n16][d=quad*8+j]
  bf16x8 qf = *(const bf16x8*)((const short*)Q + hb + (size_t)(i0w + n16) * HD + quad * 8);
  f32x4 O00 = {0.f, 0.f, 0.f, 0.f}, O01 = {0.f, 0.f, 0.f, 0.f};
  f32x4 O10 = {0.f, 0.f, 0.f, 0.f}, O11 = {0.f, 0.f, 0.f, 0.f};
  const f32x4 zero = {0.f, 0.f, 0.f, 0.f};
  float l_lane = 0.f;

  for (int jt = 0; jt < 16; ++jt) {
    gload16(Kf + fb + ((size_t)jt * 4 * 64 + t) * 8, &Ksh[t * 8]);
    gload16(Vf + fb + ((size_t)jt * 4 * 64 + t) * 8, &Vsh[t * 8]);
    __syncthreads();
    f32x4 S[4];
#pragma unroll
    for (int kk = 0; kk < 4; ++kk) {
      bf16x8 kfr = *(const bf16x8*)&Ksh[(kk * 64 + lane) * 8];
      S[kk] = __builtin_amdgcn_mfma_f32_16x16x32_bf16(kfr, qf, zero, 0, 0, 0);
    }
    bf16x4 pfA[4];
#pragma unroll
    for (int kk = 0; kk < 4; ++kk) {
      float e0 = __builtin_amdgcn_exp2f(S[kk][0]);
      float e1 = __builtin_amdgcn_exp2f(S[kk][1]);
      float e2 = __builtin_amdgcn_exp2f(S[kk][2]);
      float e3 = __builtin_amdgcn_exp2f(S[kk][3]);
      l_lane += (e0 + e1) + (e2 + e3);
      u32x2 pk;
      pk.x = pack_bf16_trunc(e0, e1);
      pk.y = pack_bf16_trunc(e2, e3);
      pfA[kk] = __builtin_bit_cast(bf16x4, pk);
    }
#pragma unroll
    for (int kk = 0; kk < 4; ++kk) {
      bf16x8 vv = *(const bf16x8*)&Vsh[(kk * 64 + lane) * 8];
      bf16x4 v0 = __builtin_shufflevector(vv, vv, 0, 1, 2, 3);
      bf16x4 v1 = __builtin_shufflevector(vv, vv, 4, 5, 6, 7);
      if (kk & 1) {
        O01 = __builtin_amdgcn_mfma_f32_16x16x16bf16_1k(pfA[kk], v0, O01, 0, 0, 0);
        O11 = __builtin_amdgcn_mfma_f32_16x16x16bf16_1k(pfA[kk], v1, O11, 0, 0, 0);
      } else {
        O00 = __builtin_amdgcn_mfma_f32_16x16x16bf16_1k(pfA[kk], v0, O00, 0, 0, 0);
        O10 = __builtin_amdgcn_mfma_f32_16x16x16bf16_1k(pfA[kk], v1, O10, 0, 0, 0);
      }
    }
    __syncthreads();  // protect LDS before next tile's DMA
  }
  f32x4 O0, O1;
#pragma unroll
  for (int r = 0; r < 4; ++r) { O0[r] = O00[r] + O01[r]; O1[r] = O10[r] + O11[r]; }
  l_lane += __shfl_xor(l_lane, 16, 64);
  l_lane += __shfl_xor(l_lane, 32, 64);
  float linv = 1.f / l_lane;                      // valid for query = n16
  float lq[4];
#pragma unroll
  for (int r = 0; r < 4; ++r) lq[r] = __shfl(linv, quad * 4 + r, 64);
  const int bb = bh >> 3, head = bh & 7;
  unsigned short* dst = Ab + (size_t)bb * (HW * CCH) + head * 32;
#pragma unroll
  for (int r = 0; r < 4; ++r) {
    int p = i0w + quad * 4 + r;
    dst[(size_t)p * CCH + n16] = bf16bits(O0[r] * lq[r]);
    dst[(size_t)p * CCH + 16 + n16] = bf16bits(O1[r] * lq[r]);
  }
}

// ---------------------------------------------------------------------------
// Kernel 3: proj MFMA GEMM -> P bf16 [b][c][p] + fused GN partial sums
// ---------------------------------------------------------------------------
__global__ __launch_bounds__(256) void proj_mfma(const unsigned short* __restrict__ Wb,
                                                 const unsigned short* __restrict__ At,
                                                 unsigned short* __restrict__ Pb,
                                                 float* __restrict__ gstats) {
  __shared__ unsigned short A_l[8 * 128 * 8];
  __shared__ unsigned short B_l[8 * 128 * 8];
  const int t = threadIdx.x;
  const int wave = t >> 6, lane = t & 63;
  const int quad = lane >> 4, n16 = lane & 15;
  const int o0 = blockIdx.x * 128;
  const int p0 = blockIdx.y * 128;
  const int b = blockIdx.z;
  const int wm = (wave >> 1) * 64, wn = (wave & 1) * 64;
  const unsigned short* Ax = At + (size_t)b * (HW * CCH);

  f32x4 acc[4][4] = {};
  for (int k0 = 0; k0 < CCH; k0 += 64) {
#pragma unroll
    for (int i = 0; i < 4; ++i) {
      int f = i * 256 + t;
      int kc = f >> 7, m = f & 127;
      int dst = (i * 256 + wave * 64) * 8;
      gload16(Wb + (size_t)(o0 + m) * CCH + k0 + kc * 8, &A_l[dst]);
      gload16(Ax + (size_t)(p0 + m) * CCH + k0 + kc * 8, &B_l[dst]);
    }
    __syncthreads();
#pragma unroll
    for (int ks = 0; ks < 2; ++ks) {
      bf16x8 af[4], bfr[4];
#pragma unroll
      for (int mi = 0; mi < 4; ++mi)
        af[mi] = *(const bf16x8*)&A_l[((ks * 4 + quad) * 128 + wm + mi * 16 + n16) * 8];
#pragma unroll
      for (int ni = 0; ni < 4; ++ni)
        bfr[ni] = *(const bf16x8*)&B_l[((ks * 4 + quad) * 128 + wn + ni * 16 + n16) * 8];
#pragma unroll
      for (int mi = 0; mi < 4; ++mi)
#pragma unroll
        for (int ni = 0; ni < 4; ++ni)
          acc[mi][ni] = __builtin_amdgcn_mfma_f32_16x16x32_bf16(af[mi], bfr[ni], acc[mi][ni], 0, 0, 0);
    }
    __syncthreads();
  }
#pragma unroll
  for (int mi = 0; mi < 4; ++mi) {
    int obase = o0 + wm + mi * 16;       // 16-aligned; group = obase>>5 wave-uniform
    int o = obase + quad * 4;
    float s1 = 0.f, s2 = 0.f;
#pragma unroll
    for (int ni = 0; ni < 4; ++ni) {
      int p = p0 + wn + ni * 16 + n16;
#pragma unroll
      for (int r = 0; r < 4; ++r) {
        float v = acc[mi][ni][r];
        s1 += v; s2 += v * v;
        Pb[(size_t)b * (CCH * HW) + (size_t)(o + r) * HW + p] = bf16bits(v);
      }
    }
#pragma unroll
    for (int m = 1; m < 64; m <<= 1) {
      s1 += __shfl_xor(s1, m, 64);
      s2 += __shfl_xor(s2, m, 64);
    }
    if (lane == 0) {
      int bg = b * 8 + (obase >> 5);
      atomicAdd(&gstats[bg * 2], s1);
      atomicAdd(&gstats[bg * 2 + 1], s2);
    }
  }
}

// ---------------------------------------------------------------------------
// Kernel 4: out = (P - mean)*inv*gamma + beta + x   (P bf16, stats from sums)
// ---------------------------------------------------------------------------
__global__ __launch_bounds__(256) void gn_apply(const unsigned short* __restrict__ Pb,
                                                const float* __restrict__ x,
                                                const float* __restrict__ gamma,
                                                const float* __restrict__ beta,
                                                const float* __restrict__ gstats,
                                                float* __restrict__ out) {
  int i4 = blockIdx.x * 256 + threadIdx.x;
  int c = (i4 >> 8) & 255;
  int bg = i4 >> 13;
  float mean = gstats[bg * 2] * (1.f / 32768.f);
  float var = gstats[bg * 2 + 1] * (1.f / 32768.f) - mean * mean;
  float inv = rsqrtf(var + 1e-5f);
  float ga = gamma[c] * inv;
  float be = beta[c] - mean * ga;
  ushort4 pu = ((const ushort4*)Pb)[i4];
  float4 xr = ((const float4*)x)[i4];
  float4 o;
  o.x = __uint_as_float((unsigned)pu.x << 16) * ga + be + xr.x;
  o.y = __uint_as_float((unsigned)pu.y << 16) * ga + be + xr.y;
  o.z = __uint_as_float((unsigned)pu.z << 16) * ga + be + xr.z;
  o.w = __uint_as_float((unsigned)pu.w << 16) * ga + be + xr.w;
  ((float4*)out)[i4] = o;
}

// ---------------------------------------------------------------------------
extern "C" void kernel_launch(void* const* d_in, const int* in_sizes, int n_in,
                              void* d_out, int out_size, void* d_ws, size_t ws_size,
                              hipStream_t stream) {
  const float* x      = (const float*)d_in[0];
  const float* w_qkv  = (const float*)d_in[1];
  const float* w_proj = (const float*)d_in[2];
  const float* gamma  = (const float*)d_in[3];
  const float* beta   = (const float*)d_in[4];
  float* out = (float*)d_out;

  const size_t SZ = (size_t)BATCH * CCH * HW;
  unsigned short* Pb = (unsigned short*)d_ws;  // bf16 [b][c][p]
  unsigned short* Qb  = Pb + SZ;
  unsigned short* Kfr = Qb + SZ;   // frag-major K
  unsigned short* Vfr = Kfr + SZ;  // frag-major V
  unsigned short* Ab  = Vfr + SZ;
  unsigned short* Xtb = Ab + SZ;
  unsigned short* Wqb = Xtb + SZ;
  unsigned short* Wpb = Wqb + (3 * CCH * CCH);
  float* gstats = (float*)(Wpb + CCH * CCH);   // 256 floats (128 bg x {s1,s2})

  prep<<<256, 256, 0, stream>>>(w_qkv, w_proj, Wqb, Wpb, gstats);
  cvt_x<<<dim3(16, 4, BATCH), 256, 0, stream>>>(x, Xtb);
  qkv_mfma<<<dim3(6, 8, BATCH), 256, 0, stream>>>(Wqb, Xtb, Qb, Kfr, Vfr);
  attn_mfma<<<dim3(16, 128), 256, 0, stream>>>(Qb, Kfr, Vfr, Ab);
  proj_mfma<<<dim3(2, 8, BATCH), 256, 0, stream>>>(Wpb, Ab, Pb, gstats);
  gn_apply<<<4096, 256, 0, stream>>>(Pb, x, gamma, beta, gstats, out);
}

// Round 9
// 155.975 us; speedup vs baseline: 1.3959x; 1.0084x over previous
//
#include <hip/hip_runtime.h>
#include <hip/hip_bf16.h>
#include <math.h>

#define BATCH 16
#define CCH 256
#define HW 1024
#define NH 8
#define HD 32
// 1/sqrt(32) * log2(e): Q pre-scaled so softmax uses raw v_exp_f32 (base-2)
#define QSCALE 0.25500526954123462f

typedef __attribute__((ext_vector_type(8))) short bf16x8;  // 8 bf16 = 4 VGPRs
typedef __attribute__((ext_vector_type(4))) short bf16x4;  // 4 bf16 = 2 VGPRs
typedef __attribute__((ext_vector_type(4))) float f32x4;
typedef __attribute__((ext_vector_type(2))) unsigned int u32x2;

__device__ __forceinline__ unsigned short bf16bits(float f) {
  __hip_bfloat16 h = __float2bfloat16(f);
  return *(unsigned short*)&h;
}

// async global->LDS, 16B per lane; lds dest must be wave-uniform base (+lane*16)
__device__ __forceinline__ void gload16(const void* g, void* l) {
  __builtin_amdgcn_global_load_lds(
      (const __attribute__((address_space(1))) unsigned int*)g,
      (__attribute__((address_space(3))) unsigned int*)l, 16, 0, 0);
}

// pack hi16 of two floats (truncation-to-bf16): dst = (hi(b)<<16)|hi(a)
__device__ __forceinline__ unsigned int pack_bf16_trunc(float a, float b) {
  return __builtin_amdgcn_perm(__float_as_uint(b), __float_as_uint(a), 0x07060302u);
}

// ---------------------------------------------------------------------------
// prep: convert both weight tensors fp32->bf16 and zero the GN accumulators.
// ---------------------------------------------------------------------------
__global__ __launch_bounds__(256) void prep(const float* __restrict__ wqkv,
                                            const float* __restrict__ wproj,
                                            unsigned short* __restrict__ wqb,
                                            unsigned short* __restrict__ wpb,
                                            float* __restrict__ gstats) {
  int blk = blockIdx.x;
  const float* src;
  unsigned short* dst;
  int i;
  if (blk < 192) {
    src = wqkv; dst = wqb; i = blk * 256 + threadIdx.x;
  } else {
    src = wproj; dst = wpb; i = (blk - 192) * 256 + threadIdx.x;
  }
  float4 v = ((const float4*)src)[i];
  ushort4 o;
  o.x = bf16bits(v.x); o.y = bf16bits(v.y); o.z = bf16bits(v.z); o.w = bf16bits(v.w);
  ((ushort4*)dst)[i] = o;
  if (blk == 255) gstats[threadIdx.x] = 0.f;
}

// ---------------------------------------------------------------------------
// Transpose-convert x fp32 [b][c][p] -> xt bf16 [b][p][c]
// ---------------------------------------------------------------------------
__global__ __launch_bounds__(256) void cvt_x(const float* __restrict__ x,
                                             unsigned short* __restrict__ xt) {
  __shared__ unsigned short tile[64][72];
  const int t = threadIdx.x;
  const int p0 = blockIdx.x * 64;
  const int c0 = blockIdx.y * 64;
  const int b = blockIdx.z;
  const float* xb = x + (size_t)b * CCH * HW;
#pragma unroll
  for (int i = 0; i < 4; ++i) {
    int f = i * 256 + t;
    int c = f >> 4, p4 = f & 15;
    float4 v = *(const float4*)(xb + (size_t)(c0 + c) * HW + p0 + p4 * 4);
    tile[p4 * 4 + 0][c] = bf16bits(v.x);
    tile[p4 * 4 + 1][c] = bf16bits(v.y);
    tile[p4 * 4 + 2][c] = bf16bits(v.z);
    tile[p4 * 4 + 3][c] = bf16bits(v.w);
  }
  __syncthreads();
  unsigned short* xtb = xt + (size_t)b * HW * CCH;
#pragma unroll
  for (int i = 0; i < 4; ++i) {
    int f = i * 256 + t;
    int p = f >> 4, c4 = f & 15;
    ushort4 v = *(const ushort4*)&tile[p][c4 * 4];
    *(ushort4*)(xtb + (size_t)(p0 + p) * CCH + c0 + c4 * 4) = v;
  }
}

// ---------------------------------------------------------------------------
// Kernel 1: qkv MFMA GEMM (128x128 tile, BK=64, global_load_lds 16B).
// Q written with QSCALE (1/sqrt(d) * log2e); K/V fragment-major.
// ---------------------------------------------------------------------------
__global__ __launch_bounds__(256) void qkv_mfma(const unsigned short* __restrict__ Wb,
                                                const unsigned short* __restrict__ Xt,
                                                unsigned short* __restrict__ Qb,
                                                unsigned short* __restrict__ Kf,
                                                unsigned short* __restrict__ Vf) {
  __shared__ unsigned short A_l[8 * 128 * 8];  // 16 KB
  __shared__ unsigned short B_l[8 * 128 * 8];  // 16 KB
  const int t = threadIdx.x;
  const int wave = t >> 6, lane = t & 63;
  const int quad = lane >> 4, n16 = lane & 15;
  const int o0 = blockIdx.x * 128;
  const int p0 = blockIdx.y * 128;
  const int b = blockIdx.z;
  const int wm = (wave >> 1) * 64, wn = (wave & 1) * 64;
  const unsigned short* Xb = Xt + (size_t)b * (HW * CCH);

  f32x4 acc[4][4] = {};
  for (int k0 = 0; k0 < CCH; k0 += 64) {
#pragma unroll
    for (int i = 0; i < 4; ++i) {
      int f = i * 256 + t;
      int kc = f >> 7, m = f & 127;
      int dst = (i * 256 + wave * 64) * 8;  // wave-uniform
      gload16(Wb + (size_t)(o0 + m) * CCH + k0 + kc * 8, &A_l[dst]);
      gload16(Xb + (size_t)(p0 + m) * CCH + k0 + kc * 8, &B_l[dst]);
    }
    __syncthreads();
#pragma unroll
    for (int ks = 0; ks < 2; ++ks) {
      bf16x8 af[4], bfr[4];
#pragma unroll
      for (int mi = 0; mi < 4; ++mi)
        af[mi] = *(const bf16x8*)&A_l[((ks * 4 + quad) * 128 + wm + mi * 16 + n16) * 8];
#pragma unroll
      for (int ni = 0; ni < 4; ++ni)
        bfr[ni] = *(const bf16x8*)&B_l[((ks * 4 + quad) * 128 + wn + ni * 16 + n16) * 8];
#pragma unroll
      for (int mi = 0; mi < 4; ++mi)
#pragma unroll
        for (int ni = 0; ni < 4; ++ni)
          acc[mi][ni] = __builtin_amdgcn_mfma_f32_16x16x32_bf16(af[mi], bfr[ni], acc[mi][ni], 0, 0, 0);
    }
    __syncthreads();
  }
  const int three = o0 >> 8;
#pragma unroll
  for (int mi = 0; mi < 4; ++mi) {
    int o = o0 + wm + mi * 16 + quad * 4;
    int head = (o >> 5) & 7;           // constant across r (d0+3 <= 31)
    int d0 = (mi & 1) * 16 + quad * 4; // o & 31
    size_t bh64 = (size_t)(b * NH + head) * 64;
    size_t bh_base = (size_t)(b * NH + head) * (HW * HD);
#pragma unroll
    for (int ni = 0; ni < 4; ++ni) {
      int p = p0 + wn + ni * 16 + n16;
      if (three == 0) {
        ushort4 st;
        st.x = bf16bits(acc[mi][ni][0] * QSCALE);
        st.y = bf16bits(acc[mi][ni][1] * QSCALE);
        st.z = bf16bits(acc[mi][ni][2] * QSCALE);
        st.w = bf16bits(acc[mi][ni][3] * QSCALE);
        *(ushort4*)&Qb[bh_base + (size_t)p * HD + d0] = st;
      } else if (three == 1) {
        int kb = p >> 4;
        size_t chunk = (bh64 + kb) * 64 + (d0 >> 3) * 16 + n16;
        ushort4 st;
        st.x = bf16bits(acc[mi][ni][0]);
        st.y = bf16bits(acc[mi][ni][1]);
        st.z = bf16bits(acc[mi][ni][2]);
        st.w = bf16bits(acc[mi][ni][3]);
        *(ushort4*)&Kf[chunk * 8 + (d0 & 7)] = st;
      } else {
        int kb = p >> 4;
        size_t base = (bh64 + kb) * 64 + (n16 >> 2) * 16 + quad * 4;
#pragma unroll
        for (int r = 0; r < 4; ++r)
          Vf[(base + r) * 8 + (mi & 1) * 4 + (n16 & 3)] = bf16bits(acc[mi][ni][r]);
      }
    }
  }
}

// ---------------------------------------------------------------------------
// Kernel 2: MFMA flash attention v7 -- 32 queries/wave (2 Q-frags per K/V LDS
// read), fully interleaved per-kk (QK -> exp2 -> pack -> PV so temps die
// immediately), launch_bounds(256,4) caps VGPR at 128 (r6's 256-VGPR spill
// came from phase-separated liveness + address-taken pack locals).
// Block = 4 waves x 32 q = 128 queries of one bh; waves share K/V LDS tile.
// ---------------------------------------------------------------------------
__global__ __launch_bounds__(256, 4) void attn_mfma(const unsigned short* __restrict__ Q,
                                                    const unsigned short* __restrict__ Kf,
                                                    const unsigned short* __restrict__ Vf,
                                                    unsigned short* __restrict__ Ab) {
  __shared__ unsigned short Ksh[4 * 64 * 8];  // 4 KB
  __shared__ unsigned short Vsh[4 * 64 * 8];  // 4 KB
  const int t = threadIdx.x;
  const int lane = t & 63;
  const int quad = lane >> 4, n16 = lane & 15;
  const int wave = t >> 6;
  // XCD swizzle: all 8 query-tiles of a (b,head) on one XCD slot
  const int id = blockIdx.y * 8 + blockIdx.x;  // 1024 blocks
  const int xcd = id & 7, jj = id >> 3;        // jj 0..127
  const int bh = xcd * 16 + (jj >> 3);
  const int qtile = jj & 7;
  const int i0w = qtile * 128 + wave * 32;
  const size_t hb = (size_t)bh * (HW * HD);
  const size_t fb = (size_t)bh * 64 * 64 * 8;

  // Q frags (B operand): B[k=quad*8+j][n=n16] = Q[query][d]
  bf16x8 qf0 = *(const bf16x8*)((const short*)Q + hb + (size_t)(i0w + n16) * HD + quad * 8);
  bf16x8 qf1 = *(const bf16x8*)((const short*)Q + hb + (size_t)(i0w + 16 + n16) * HD + quad * 8);
  // O[qgroup][dhalf][kk-parity]
  f32x4 O000 = {0,0,0,0}, O001 = {0,0,0,0}, O010 = {0,0,0,0}, O011 = {0,0,0,0};
  f32x4 O100 = {0,0,0,0}, O101 = {0,0,0,0}, O110 = {0,0,0,0}, O111 = {0,0,0,0};
  const f32x4 zero = {0.f, 0.f, 0.f, 0.f};
  float l0 = 0.f, l1 = 0.f;

  for (int jt = 0; jt < 16; ++jt) {
    gload16(Kf + fb + ((size_t)jt * 4 * 64 + t) * 8, &Ksh[t * 8]);
    gload16(Vf + fb + ((size_t)jt * 4 * 64 + t) * 8, &Vsh[t * 8]);
    __syncthreads();
#pragma unroll
    for (int kk = 0; kk < 4; ++kk) {
      bf16x8 kfr = *(const bf16x8*)&Ksh[(kk * 64 + lane) * 8];
      f32x4 S0 = __builtin_amdgcn_mfma_f32_16x16x32_bf16(kfr, qf0, zero, 0, 0, 0);
      f32x4 S1 = __builtin_amdgcn_mfma_f32_16x16x32_bf16(kfr, qf1, zero, 0, 0, 0);
      float a0 = __builtin_amdgcn_exp2f(S0[0]);
      float a1 = __builtin_amdgcn_exp2f(S0[1]);
      float a2 = __builtin_amdgcn_exp2f(S0[2]);
      float a3 = __builtin_amdgcn_exp2f(S0[3]);
      l0 += (a0 + a1) + (a2 + a3);
      u32x2 pkw0;
      pkw0.x = pack_bf16_trunc(a0, a1);
      pkw0.y = pack_bf16_trunc(a2, a3);
      bf16x4 pf0 = __builtin_bit_cast(bf16x4, pkw0);
      float b0 = __builtin_amdgcn_exp2f(S1[0]);
      float b1 = __builtin_amdgcn_exp2f(S1[1]);
      float b2 = __builtin_amdgcn_exp2f(S1[2]);
      float b3 = __builtin_amdgcn_exp2f(S1[3]);
      l1 += (b0 + b1) + (b2 + b3);
      u32x2 pkw1;
      pkw1.x = pack_bf16_trunc(b0, b1);
      pkw1.y = pack_bf16_trunc(b2, b3);
      bf16x4 pf1 = __builtin_bit_cast(bf16x4, pkw1);
      bf16x8 vv = *(const bf16x8*)&Vsh[(kk * 64 + lane) * 8];
      bf16x4 v0 = __builtin_shufflevector(vv, vv, 0, 1, 2, 3);
      bf16x4 v1 = __builtin_shufflevector(vv, vv, 4, 5, 6, 7);
      if (kk & 1) {
        O001 = __builtin_amdgcn_mfma_f32_16x16x16bf16_1k(pf0, v0, O001, 0, 0, 0);
        O011 = __builtin_amdgcn_mfma_f32_16x16x16bf16_1k(pf0, v1, O011, 0, 0, 0);
        O101 = __builtin_amdgcn_mfma_f32_16x16x16bf16_1k(pf1, v0, O101, 0, 0, 0);
        O111 = __builtin_amdgcn_mfma_f32_16x16x16bf16_1k(pf1, v1, O111, 0, 0, 0);
      } else {
        O000 = __builtin_amdgcn_mfma_f32_16x16x16bf16_1k(pf0, v0, O000, 0, 0, 0);
        O010 = __builtin_amdgcn_mfma_f32_16x16x16bf16_1k(pf0, v1, O010, 0, 0, 0);
        O100 = __builtin_amdgcn_mfma_f32_16x16x16bf16_1k(pf1, v0, O100, 0, 0, 0);
        O110 = __builtin_amdgcn_mfma_f32_16x16x16bf16_1k(pf1, v1, O110, 0, 0, 0);
      }
    }
    __syncthreads();  // protect LDS before next tile's DMA
  }
  f32x4 A0, A1, B0, B1;
#pragma unroll
  for (int r = 0; r < 4; ++r) {
    A0[r] = O000[r] + O001[r]; A1[r] = O010[r] + O011[r];
    B0[r] = O100[r] + O101[r]; B1[r] = O110[r] + O111[r];
  }
  l0 += __shfl_xor(l0, 16, 64); l0 += __shfl_xor(l0, 32, 64);
  l1 += __shfl_xor(l1, 16, 64); l1 += __shfl_xor(l1, 32, 64);
  float linv0 = 1.f / l0, linv1 = 1.f / l1;
  float lq0[4], lq1[4];
#pragma unroll
  for (int r = 0; r < 4; ++r) {
    lq0[r] = __shfl(linv0, quad * 4 + r, 64);
    lq1[r] = __shfl(linv1, quad * 4 + r, 64);
  }
  const int bb = bh >> 3, head = bh & 7;
  unsigned short* dst = Ab + (size_t)bb * (HW * CCH) + head * 32;
#pragma unroll
  for (int r = 0; r < 4; ++r) {
    int p0r = i0w + quad * 4 + r;
    dst[(size_t)p0r * CCH + n16] = bf16bits(A0[r] * lq0[r]);
    dst[(size_t)p0r * CCH + 16 + n16] = bf16bits(A1[r] * lq0[r]);
    int p1r = i0w + 16 + quad * 4 + r;
    dst[(size_t)p1r * CCH + n16] = bf16bits(B0[r] * lq1[r]);
    dst[(size_t)p1r * CCH + 16 + n16] = bf16bits(B1[r] * lq1[r]);
  }
}

// ---------------------------------------------------------------------------
// Kernel 3: proj MFMA GEMM -> P bf16 [b][c][p] + fused GN partial sums
// ---------------------------------------------------------------------------
__global__ __launch_bounds__(256) void proj_mfma(const unsigned short* __restrict__ Wb,
                                                 const unsigned short* __restrict__ At,
                                                 unsigned short* __restrict__ Pb,
                                                 float* __restrict__ gstats) {
  __shared__ unsigned short A_l[8 * 128 * 8];
  __shared__ unsigned short B_l[8 * 128 * 8];
  const int t = threadIdx.x;
  const int wave = t >> 6, lane = t & 63;
  const int quad = lane >> 4, n16 = lane & 15;
  const int o0 = blockIdx.x * 128;
  const int p0 = blockIdx.y * 128;
  const int b = blockIdx.z;
  const int wm = (wave >> 1) * 64, wn = (wave & 1) * 64;
  const unsigned short* Ax = At + (size_t)b * (HW * CCH);

  f32x4 acc[4][4] = {};
  for (int k0 = 0; k0 < CCH; k0 += 64) {
#pragma unroll
    for (int i = 0; i < 4; ++i) {
      int f = i * 256 + t;
      int kc = f >> 7, m = f & 127;
      int dst = (i * 256 + wave * 64) * 8;
      gload16(Wb + (size_t)(o0 + m) * CCH + k0 + kc * 8, &A_l[dst]);
      gload16(Ax + (size_t)(p0 + m) * CCH + k0 + kc * 8, &B_l[dst]);
    }
    __syncthreads();
#pragma unroll
    for (int ks = 0; ks < 2; ++ks) {
      bf16x8 af[4], bfr[4];
#pragma unroll
      for (int mi = 0; mi < 4; ++mi)
        af[mi] = *(const bf16x8*)&A_l[((ks * 4 + quad) * 128 + wm + mi * 16 + n16) * 8];
#pragma unroll
      for (int ni = 0; ni < 4; ++ni)
        bfr[ni] = *(const bf16x8*)&B_l[((ks * 4 + quad) * 128 + wn + ni * 16 + n16) * 8];
#pragma unroll
      for (int mi = 0; mi < 4; ++mi)
#pragma unroll
        for (int ni = 0; ni < 4; ++ni)
          acc[mi][ni] = __builtin_amdgcn_mfma_f32_16x16x32_bf16(af[mi], bfr[ni], acc[mi][ni], 0, 0, 0);
    }
    __syncthreads();
  }
#pragma unroll
  for (int mi = 0; mi < 4; ++mi) {
    int obase = o0 + wm + mi * 16;       // 16-aligned; group = obase>>5 wave-uniform
    int o = obase + quad * 4;
    float s1 = 0.f, s2 = 0.f;
#pragma unroll
    for (int ni = 0; ni < 4; ++ni) {
      int p = p0 + wn + ni * 16 + n16;
#pragma unroll
      for (int r = 0; r < 4; ++r) {
        float v = acc[mi][ni][r];
        s1 += v; s2 += v * v;
        Pb[(size_t)b * (CCH * HW) + (size_t)(o + r) * HW + p] = bf16bits(v);
      }
    }
#pragma unroll
    for (int m = 1; m < 64; m <<= 1) {
      s1 += __shfl_xor(s1, m, 64);
      s2 += __shfl_xor(s2, m, 64);
    }
    if (lane == 0) {
      int bg = b * 8 + (obase >> 5);
      atomicAdd(&gstats[bg * 2], s1);
      atomicAdd(&gstats[bg * 2 + 1], s2);
    }
  }
}

// ---------------------------------------------------------------------------
// Kernel 4: out = (P - mean)*inv*gamma + beta + x   (P bf16, stats from sums)
// ---------------------------------------------------------------------------
__global__ __launch_bounds__(256) void gn_apply(const unsigned short* __restrict__ Pb,
                                                const float* __restrict__ x,
                                                const float* __restrict__ gamma,
                                                const float* __restrict__ beta,
                                                const float* __restrict__ gstats,
                                                float* __restrict__ out) {
  int i4 = blockIdx.x * 256 + threadIdx.x;
  int c = (i4 >> 8) & 255;
  int bg = i4 >> 13;
  float mean = gstats[bg * 2] * (1.f / 32768.f);
  float var = gstats[bg * 2 + 1] * (1.f / 32768.f) - mean * mean;
  float inv = rsqrtf(var + 1e-5f);
  float ga = gamma[c] * inv;
  float be = beta[c] - mean * ga;
  ushort4 pu = ((const ushort4*)Pb)[i4];
  float4 xr = ((const float4*)x)[i4];
  float4 o;
  o.x = __uint_as_float((unsigned)pu.x << 16) * ga + be + xr.x;
  o.y = __uint_as_float((unsigned)pu.y << 16) * ga + be + xr.y;
  o.z = __uint_as_float((unsigned)pu.z << 16) * ga + be + xr.z;
  o.w = __uint_as_float((unsigned)pu.w << 16) * ga + be + xr.w;
  ((float4*)out)[i4] = o;
}

// ---------------------------------------------------------------------------
extern "C" void kernel_launch(void* const* d_in, const int* in_sizes, int n_in,
                              void* d_out, int out_size, void* d_ws, size_t ws_size,
                              hipStream_t stream) {
  const float* x      = (const float*)d_in[0];
  const float* w_qkv  = (const float*)d_in[1];
  const float* w_proj = (const float*)d_in[2];
  const float* gamma  = (const float*)d_in[3];
  const float* beta   = (const float*)d_in[4];
  float* out = (float*)d_out;

  const size_t SZ = (size_t)BATCH * CCH * HW;
  unsigned short* Pb = (unsigned short*)d_ws;  // bf16 [b][c][p]
  unsigned short* Qb  = Pb + SZ;
  unsigned short* Kfr = Qb + SZ;   // frag-major K
  unsigned short* Vfr = Kfr + SZ;  // frag-major V
  unsigned short* Ab  = Vfr + SZ;
  unsigned short* Xtb = Ab + SZ;
  unsigned short* Wqb = Xtb + SZ;
  unsigned short* Wpb = Wqb + (3 * CCH * CCH);
  float* gstats = (float*)(Wpb + CCH * CCH);   // 256 floats (128 bg x {s1,s2})

  prep<<<256, 256, 0, stream>>>(w_qkv, w_proj, Wqb, Wpb, gstats);
  cvt_x<<<dim3(16, 4, BATCH), 256, 0, stream>>>(x, Xtb);
  qkv_mfma<<<dim3(6, 8, BATCH), 256, 0, stream>>>(Wqb, Xtb, Qb, Kfr, Vfr);
  attn_mfma<<<dim3(8, 128), 256, 0, stream>>>(Qb, Kfr, Vfr, Ab);
  proj_mfma<<<dim3(2, 8, BATCH), 256, 0, stream>>>(Wpb, Ab, Pb, gstats);
  gn_apply<<<4096, 256, 0, stream>>>(Pb, x, gamma, beta, gstats, out);
}

// Round 10
// 154.896 us; speedup vs baseline: 1.4056x; 1.0070x over previous
//
#include <hip/hip_runtime.h>
#include <hip/hip_bf16.h>
#include <math.h>

#define BATCH 16
#define CCH 256
#define HW 1024
#define NH 8
#define HD 32
// 1/sqrt(32) * log2(e): Q pre-scaled so softmax uses raw v_exp_f32 (base-2)
#define QSCALE 0.25500526954123462f

typedef __attribute__((ext_vector_type(8))) short bf16x8;  // 8 bf16 = 4 VGPRs
typedef __attribute__((ext_vector_type(4))) short bf16x4;  // 4 bf16 = 2 VGPRs
typedef __attribute__((ext_vector_type(4))) float f32x4;
typedef __attribute__((ext_vector_type(2))) unsigned int u32x2;

__device__ __forceinline__ unsigned short bf16bits(float f) {
  __hip_bfloat16 h = __float2bfloat16(f);
  return *(unsigned short*)&h;
}

// async global->LDS, 16B per lane; lds dest must be wave-uniform base (+lane*16)
__device__ __forceinline__ void gload16(const void* g, void* l) {
  __builtin_amdgcn_global_load_lds(
      (const __attribute__((address_space(1))) unsigned int*)g,
      (__attribute__((address_space(3))) unsigned int*)l, 16, 0, 0);
}

// pack hi16 of two floats (truncation-to-bf16): dst = (hi(b)<<16)|hi(a)
__device__ __forceinline__ unsigned int pack_bf16_trunc(float a, float b) {
  return __builtin_amdgcn_perm(__float_as_uint(b), __float_as_uint(a), 0x07060302u);
}

// ---------------------------------------------------------------------------
// cvt_x + weight prep fused. Grid (16,5,16):
//   y<4 : transpose-convert x fp32 [b][c][p] -> xt bf16 [b][p][c]
//   y==4: blocks (z*16+x) = 0..255 convert w_qkv (0..191) / w_proj (192..255)
//         fp32->bf16; block 255 also zeros the GN accumulators.
// ---------------------------------------------------------------------------
__global__ __launch_bounds__(256) void cvt_x(const float* __restrict__ x,
                                             unsigned short* __restrict__ xt,
                                             const float* __restrict__ wqkv,
                                             const float* __restrict__ wproj,
                                             unsigned short* __restrict__ wqb,
                                             unsigned short* __restrict__ wpb,
                                             float* __restrict__ gstats) {
  __shared__ unsigned short tile[64][72];
  const int t = threadIdx.x;
  if (blockIdx.y == 4) {
    int wblk = blockIdx.z * 16 + blockIdx.x;  // 0..255
    const float* src;
    unsigned short* dst;
    int i;
    if (wblk < 192) {
      src = wqkv; dst = wqb; i = wblk * 256 + t;
    } else {
      src = wproj; dst = wpb; i = (wblk - 192) * 256 + t;
    }
    float4 v = ((const float4*)src)[i];
    ushort4 o;
    o.x = bf16bits(v.x); o.y = bf16bits(v.y); o.z = bf16bits(v.z); o.w = bf16bits(v.w);
    ((ushort4*)dst)[i] = o;
    if (wblk == 255) gstats[t] = 0.f;
    return;
  }
  const int p0 = blockIdx.x * 64;
  const int c0 = blockIdx.y * 64;
  const int b = blockIdx.z;
  const float* xb = x + (size_t)b * CCH * HW;
#pragma unroll
  for (int i = 0; i < 4; ++i) {
    int f = i * 256 + t;
    int c = f >> 4, p4 = f & 15;
    float4 v = *(const float4*)(xb + (size_t)(c0 + c) * HW + p0 + p4 * 4);
    tile[p4 * 4 + 0][c] = bf16bits(v.x);
    tile[p4 * 4 + 1][c] = bf16bits(v.y);
    tile[p4 * 4 + 2][c] = bf16bits(v.z);
    tile[p4 * 4 + 3][c] = bf16bits(v.w);
  }
  __syncthreads();
  unsigned short* xtb = xt + (size_t)b * HW * CCH;
#pragma unroll
  for (int i = 0; i < 4; ++i) {
    int f = i * 256 + t;
    int p = f >> 4, c4 = f & 15;
    ushort4 v = *(const ushort4*)&tile[p][c4 * 4];
    *(ushort4*)(xtb + (size_t)(p0 + p) * CCH + c0 + c4 * 4) = v;
  }
}

// ---------------------------------------------------------------------------
// Kernel 1: qkv MFMA GEMM (128x128 tile, BK=64, global_load_lds 16B).
// Q written with QSCALE (1/sqrt(d) * log2e); K/V fragment-major.
// ---------------------------------------------------------------------------
__global__ __launch_bounds__(256) void qkv_mfma(const unsigned short* __restrict__ Wb,
                                                const unsigned short* __restrict__ Xt,
                                                unsigned short* __restrict__ Qb,
                                                unsigned short* __restrict__ Kf,
                                                unsigned short* __restrict__ Vf) {
  __shared__ unsigned short A_l[8 * 128 * 8];  // 16 KB
  __shared__ unsigned short B_l[8 * 128 * 8];  // 16 KB
  const int t = threadIdx.x;
  const int wave = t >> 6, lane = t & 63;
  const int quad = lane >> 4, n16 = lane & 15;
  const int o0 = blockIdx.x * 128;
  const int p0 = blockIdx.y * 128;
  const int b = blockIdx.z;
  const int wm = (wave >> 1) * 64, wn = (wave & 1) * 64;
  const unsigned short* Xb = Xt + (size_t)b * (HW * CCH);

  f32x4 acc[4][4] = {};
  for (int k0 = 0; k0 < CCH; k0 += 64) {
#pragma unroll
    for (int i = 0; i < 4; ++i) {
      int f = i * 256 + t;
      int kc = f >> 7, m = f & 127;
      int dst = (i * 256 + wave * 64) * 8;  // wave-uniform
      gload16(Wb + (size_t)(o0 + m) * CCH + k0 + kc * 8, &A_l[dst]);
      gload16(Xb + (size_t)(p0 + m) * CCH + k0 + kc * 8, &B_l[dst]);
    }
    __syncthreads();
#pragma unroll
    for (int ks = 0; ks < 2; ++ks) {
      bf16x8 af[4], bfr[4];
#pragma unroll
      for (int mi = 0; mi < 4; ++mi)
        af[mi] = *(const bf16x8*)&A_l[((ks * 4 + quad) * 128 + wm + mi * 16 + n16) * 8];
#pragma unroll
      for (int ni = 0; ni < 4; ++ni)
        bfr[ni] = *(const bf16x8*)&B_l[((ks * 4 + quad) * 128 + wn + ni * 16 + n16) * 8];
#pragma unroll
      for (int mi = 0; mi < 4; ++mi)
#pragma unroll
        for (int ni = 0; ni < 4; ++ni)
          acc[mi][ni] = __builtin_amdgcn_mfma_f32_16x16x32_bf16(af[mi], bfr[ni], acc[mi][ni], 0, 0, 0);
    }
    __syncthreads();
  }
  const int three = o0 >> 8;
#pragma unroll
  for (int mi = 0; mi < 4; ++mi) {
    int o = o0 + wm + mi * 16 + quad * 4;
    int head = (o >> 5) & 7;           // constant across r (d0+3 <= 31)
    int d0 = (mi & 1) * 16 + quad * 4; // o & 31
    size_t bh64 = (size_t)(b * NH + head) * 64;
    size_t bh_base = (size_t)(b * NH + head) * (HW * HD);
#pragma unroll
    for (int ni = 0; ni < 4; ++ni) {
      int p = p0 + wn + ni * 16 + n16;
      if (three == 0) {
        ushort4 st;
        st.x = bf16bits(acc[mi][ni][0] * QSCALE);
        st.y = bf16bits(acc[mi][ni][1] * QSCALE);
        st.z = bf16bits(acc[mi][ni][2] * QSCALE);
        st.w = bf16bits(acc[mi][ni][3] * QSCALE);
        *(ushort4*)&Qb[bh_base + (size_t)p * HD + d0] = st;
      } else if (three == 1) {
        int kb = p >> 4;
        size_t chunk = (bh64 + kb) * 64 + (d0 >> 3) * 16 + n16;
        ushort4 st;
        st.x = bf16bits(acc[mi][ni][0]);
        st.y = bf16bits(acc[mi][ni][1]);
        st.z = bf16bits(acc[mi][ni][2]);
        st.w = bf16bits(acc[mi][ni][3]);
        *(ushort4*)&Kf[chunk * 8 + (d0 & 7)] = st;
      } else {
        int kb = p >> 4;
        size_t base = (bh64 + kb) * 64 + (n16 >> 2) * 16 + quad * 4;
#pragma unroll
        for (int r = 0; r < 4; ++r)
          Vf[(base + r) * 8 + (mi & 1) * 4 + (n16 & 3)] = bf16bits(acc[mi][ni][r]);
      }
    }
  }
}

// ---------------------------------------------------------------------------
// Kernel 2: MFMA flash attention (r9 v7: 32 q/wave, interleaved per-kk,
// launch_bounds(256,4)).
// ---------------------------------------------------------------------------
__global__ __launch_bounds__(256, 4) void attn_mfma(const unsigned short* __restrict__ Q,
                                                    const unsigned short* __restrict__ Kf,
                                                    const unsigned short* __restrict__ Vf,
                                                    unsigned short* __restrict__ Ab) {
  __shared__ unsigned short Ksh[4 * 64 * 8];  // 4 KB
  __shared__ unsigned short Vsh[4 * 64 * 8];  // 4 KB
  const int t = threadIdx.x;
  const int lane = t & 63;
  const int quad = lane >> 4, n16 = lane & 15;
  const int wave = t >> 6;
  const int id = blockIdx.y * 8 + blockIdx.x;  // 1024 blocks
  const int xcd = id & 7, jj = id >> 3;        // jj 0..127
  const int bh = xcd * 16 + (jj >> 3);
  const int qtile = jj & 7;
  const int i0w = qtile * 128 + wave * 32;
  const size_t hb = (size_t)bh * (HW * HD);
  const size_t fb = (size_t)bh * 64 * 64 * 8;

  bf16x8 qf0 = *(const bf16x8*)((const short*)Q + hb + (size_t)(i0w + n16) * HD + quad * 8);
  bf16x8 qf1 = *(const bf16x8*)((const short*)Q + hb + (size_t)(i0w + 16 + n16) * HD + quad * 8);
  f32x4 O000 = {0,0,0,0}, O001 = {0,0,0,0}, O010 = {0,0,0,0}, O011 = {0,0,0,0};
  f32x4 O100 = {0,0,0,0}, O101 = {0,0,0,0}, O110 = {0,0,0,0}, O111 = {0,0,0,0};
  const f32x4 zero = {0.f, 0.f, 0.f, 0.f};
  float l0 = 0.f, l1 = 0.f;

  for (int jt = 0; jt < 16; ++jt) {
    gload16(Kf + fb + ((size_t)jt * 4 * 64 + t) * 8, &Ksh[t * 8]);
    gload16(Vf + fb + ((size_t)jt * 4 * 64 + t) * 8, &Vsh[t * 8]);
    __syncthreads();
#pragma unroll
    for (int kk = 0; kk < 4; ++kk) {
      bf16x8 kfr = *(const bf16x8*)&Ksh[(kk * 64 + lane) * 8];
      f32x4 S0 = __builtin_amdgcn_mfma_f32_16x16x32_bf16(kfr, qf0, zero, 0, 0, 0);
      f32x4 S1 = __builtin_amdgcn_mfma_f32_16x16x32_bf16(kfr, qf1, zero, 0, 0, 0);
      float a0 = __builtin_amdgcn_exp2f(S0[0]);
      float a1 = __builtin_amdgcn_exp2f(S0[1]);
      float a2 = __builtin_amdgcn_exp2f(S0[2]);
      float a3 = __builtin_amdgcn_exp2f(S0[3]);
      l0 += (a0 + a1) + (a2 + a3);
      u32x2 pkw0;
      pkw0.x = pack_bf16_trunc(a0, a1);
      pkw0.y = pack_bf16_trunc(a2, a3);
      bf16x4 pf0 = __builtin_bit_cast(bf16x4, pkw0);
      float b0 = __builtin_amdgcn_exp2f(S1[0]);
      float b1 = __builtin_amdgcn_exp2f(S1[1]);
      float b2 = __builtin_amdgcn_exp2f(S1[2]);
      float b3 = __builtin_amdgcn_exp2f(S1[3]);
      l1 += (b0 + b1) + (b2 + b3);
      u32x2 pkw1;
      pkw1.x = pack_bf16_trunc(b0, b1);
      pkw1.y = pack_bf16_trunc(b2, b3);
      bf16x4 pf1 = __builtin_bit_cast(bf16x4, pkw1);
      bf16x8 vv = *(const bf16x8*)&Vsh[(kk * 64 + lane) * 8];
      bf16x4 v0 = __builtin_shufflevector(vv, vv, 0, 1, 2, 3);
      bf16x4 v1 = __builtin_shufflevector(vv, vv, 4, 5, 6, 7);
      if (kk & 1) {
        O001 = __builtin_amdgcn_mfma_f32_16x16x16bf16_1k(pf0, v0, O001, 0, 0, 0);
        O011 = __builtin_amdgcn_mfma_f32_16x16x16bf16_1k(pf0, v1, O011, 0, 0, 0);
        O101 = __builtin_amdgcn_mfma_f32_16x16x16bf16_1k(pf1, v0, O101, 0, 0, 0);
        O111 = __builtin_amdgcn_mfma_f32_16x16x16bf16_1k(pf1, v1, O111, 0, 0, 0);
      } else {
        O000 = __builtin_amdgcn_mfma_f32_16x16x16bf16_1k(pf0, v0, O000, 0, 0, 0);
        O010 = __builtin_amdgcn_mfma_f32_16x16x16bf16_1k(pf0, v1, O010, 0, 0, 0);
        O100 = __builtin_amdgcn_mfma_f32_16x16x16bf16_1k(pf1, v0, O100, 0, 0, 0);
        O110 = __builtin_amdgcn_mfma_f32_16x16x16bf16_1k(pf1, v1, O110, 0, 0, 0);
      }
    }
    __syncthreads();
  }
  f32x4 A0, A1, B0, B1;
#pragma unroll
  for (int r = 0; r < 4; ++r) {
    A0[r] = O000[r] + O001[r]; A1[r] = O010[r] + O011[r];
    B0[r] = O100[r] + O101[r]; B1[r] = O110[r] + O111[r];
  }
  l0 += __shfl_xor(l0, 16, 64); l0 += __shfl_xor(l0, 32, 64);
  l1 += __shfl_xor(l1, 16, 64); l1 += __shfl_xor(l1, 32, 64);
  float linv0 = 1.f / l0, linv1 = 1.f / l1;
  float lq0[4], lq1[4];
#pragma unroll
  for (int r = 0; r < 4; ++r) {
    lq0[r] = __shfl(linv0, quad * 4 + r, 64);
    lq1[r] = __shfl(linv1, quad * 4 + r, 64);
  }
  const int bb = bh >> 3, head = bh & 7;
  unsigned short* dst = Ab + (size_t)bb * (HW * CCH) + head * 32;
#pragma unroll
  for (int r = 0; r < 4; ++r) {
    int p0r = i0w + quad * 4 + r;
    dst[(size_t)p0r * CCH + n16] = bf16bits(A0[r] * lq0[r]);
    dst[(size_t)p0r * CCH + 16 + n16] = bf16bits(A1[r] * lq0[r]);
    int p1r = i0w + 16 + quad * 4 + r;
    dst[(size_t)p1r * CCH + n16] = bf16bits(B0[r] * lq1[r]);
    dst[(size_t)p1r * CCH + 16 + n16] = bf16bits(B1[r] * lq1[r]);
  }
}

// ---------------------------------------------------------------------------
// Kernel 3: proj MFMA GEMM, 64x128 tile (512 blocks = 2/CU for latency hiding;
// per-wave 32x64, acc 2x4 frags) -> P bf16 [b][c][p] + fused GN partial sums
// ---------------------------------------------------------------------------
__global__ __launch_bounds__(256) void proj_mfma(const unsigned short* __restrict__ Wb,
                                                 const unsigned short* __restrict__ At,
                                                 unsigned short* __restrict__ Pb,
                                                 float* __restrict__ gstats) {
  __shared__ unsigned short A_l[8 * 64 * 8];   // 8 KB
  __shared__ unsigned short B_l[8 * 128 * 8];  // 16 KB
  const int t = threadIdx.x;
  const int wave = t >> 6, lane = t & 63;
  const int quad = lane >> 4, n16 = lane & 15;
  const int o0 = blockIdx.x * 64;   // 0..3
  const int p0 = blockIdx.y * 128;  // 0..7
  const int b = blockIdx.z;
  const int wm = (wave >> 1) * 32, wn = (wave & 1) * 64;
  const unsigned short* Ax = At + (size_t)b * (HW * CCH);

  f32x4 acc[2][4] = {};
  for (int k0 = 0; k0 < CCH; k0 += 64) {
#pragma unroll
    for (int i = 0; i < 2; ++i) {
      int f = i * 256 + t;
      int kc = f >> 6, m = f & 63;
      int dst = (i * 256 + wave * 64) * 8;
      gload16(Wb + (size_t)(o0 + m) * CCH + k0 + kc * 8, &A_l[dst]);
    }
#pragma unroll
    for (int i = 0; i < 4; ++i) {
      int f = i * 256 + t;
      int kc = f >> 7, m = f & 127;
      int dst = (i * 256 + wave * 64) * 8;
      gload16(Ax + (size_t)(p0 + m) * CCH + k0 + kc * 8, &B_l[dst]);
    }
    __syncthreads();
#pragma unroll
    for (int ks = 0; ks < 2; ++ks) {
      bf16x8 af[2], bfr[4];
#pragma unroll
      for (int mi = 0; mi < 2; ++mi)
        af[mi] = *(const bf16x8*)&A_l[((ks * 4 + quad) * 64 + wm + mi * 16 + n16) * 8];
#pragma unroll
      for (int ni = 0; ni < 4; ++ni)
        bfr[ni] = *(const bf16x8*)&B_l[((ks * 4 + quad) * 128 + wn + ni * 16 + n16) * 8];
#pragma unroll
      for (int mi = 0; mi < 2; ++mi)
#pragma unroll
        for (int ni = 0; ni < 4; ++ni)
          acc[mi][ni] = __builtin_amdgcn_mfma_f32_16x16x32_bf16(af[mi], bfr[ni], acc[mi][ni], 0, 0, 0);
    }
    __syncthreads();
  }
#pragma unroll
  for (int mi = 0; mi < 2; ++mi) {
    int obase = o0 + wm + mi * 16;       // 16-aligned; tile stays inside one 32-ch group
    int o = obase + quad * 4;
    float s1 = 0.f, s2 = 0.f;
#pragma unroll
    for (int ni = 0; ni < 4; ++ni) {
      int p = p0 + wn + ni * 16 + n16;
#pragma unroll
      for (int r = 0; r < 4; ++r) {
        float v = acc[mi][ni][r];
        s1 += v; s2 += v * v;
        Pb[(size_t)b * (CCH * HW) + (size_t)(o + r) * HW + p] = bf16bits(v);
      }
    }
#pragma unroll
    for (int m = 1; m < 64; m <<= 1) {
      s1 += __shfl_xor(s1, m, 64);
      s2 += __shfl_xor(s2, m, 64);
    }
    if (lane == 0) {
      int bg = b * 8 + (obase >> 5);
      atomicAdd(&gstats[bg * 2], s1);
      atomicAdd(&gstats[bg * 2 + 1], s2);
    }
  }
}

// ---------------------------------------------------------------------------
// Kernel 4: out = (P - mean)*inv*gamma + beta + x   (P bf16, stats from sums)
// ---------------------------------------------------------------------------
__global__ __launch_bounds__(256) void gn_apply(const unsigned short* __restrict__ Pb,
                                                const float* __restrict__ x,
                                                const float* __restrict__ gamma,
                                                const float* __restrict__ beta,
                                                const float* __restrict__ gstats,
                                                float* __restrict__ out) {
  int i4 = blockIdx.x * 256 + threadIdx.x;
  int c = (i4 >> 8) & 255;
  int bg = i4 >> 13;
  float mean = gstats[bg * 2] * (1.f / 32768.f);
  float var = gstats[bg * 2 + 1] * (1.f / 32768.f) - mean * mean;
  float inv = rsqrtf(var + 1e-5f);
  float ga = gamma[c] * inv;
  float be = beta[c] - mean * ga;
  ushort4 pu = ((const ushort4*)Pb)[i4];
  float4 xr = ((const float4*)x)[i4];
  float4 o;
  o.x = __uint_as_float((unsigned)pu.x << 16) * ga + be + xr.x;
  o.y = __uint_as_float((unsigned)pu.y << 16) * ga + be + xr.y;
  o.z = __uint_as_float((unsigned)pu.z << 16) * ga + be + xr.z;
  o.w = __uint_as_float((unsigned)pu.w << 16) * ga + be + xr.w;
  ((float4*)out)[i4] = o;
}

// ---------------------------------------------------------------------------
extern "C" void kernel_launch(void* const* d_in, const int* in_sizes, int n_in,
                              void* d_out, int out_size, void* d_ws, size_t ws_size,
                              hipStream_t stream) {
  const float* x      = (const float*)d_in[0];
  const float* w_qkv  = (const float*)d_in[1];
  const float* w_proj = (const float*)d_in[2];
  const float* gamma  = (const float*)d_in[3];
  const float* beta   = (const float*)d_in[4];
  float* out = (float*)d_out;

  const size_t SZ = (size_t)BATCH * CCH * HW;
  unsigned short* Pb = (unsigned short*)d_ws;  // bf16 [b][c][p]
  unsigned short* Qb  = Pb + SZ;
  unsigned short* Kfr = Qb + SZ;   // frag-major K
  unsigned short* Vfr = Kfr + SZ;  // frag-major V
  unsigned short* Ab  = Vfr + SZ;
  unsigned short* Xtb = Ab + SZ;
  unsigned short* Wqb = Xtb + SZ;
  unsigned short* Wpb = Wqb + (3 * CCH * CCH);
  float* gstats = (float*)(Wpb + CCH * CCH);   // 256 floats (128 bg x {s1,s2})

  cvt_x<<<dim3(16, 5, BATCH), 256, 0, stream>>>(x, Xtb, w_qkv, w_proj, Wqb, Wpb, gstats);
  qkv_mfma<<<dim3(6, 8, BATCH), 256, 0, stream>>>(Wqb, Xtb, Qb, Kfr, Vfr);
  attn_mfma<<<dim3(8, 128), 256, 0, stream>>>(Qb, Kfr, Vfr, Ab);
  proj_mfma<<<dim3(4, 8, BATCH), 256, 0, stream>>>(Wpb, Ab, Pb, gstats);
  gn_apply<<<4096, 256, 0, stream>>>(Pb, x, gamma, beta, gstats, out);
}